// Round 6
// baseline (1747.941 us; speedup 1.0000x reference)
//
#include <hip/hip_runtime.h>
#include <hip/hip_fp16.h>

// HierarchicalEncoder: 6× (GCN -> BN -> ReLU) with level pooling + final linear.
// dst-CSR built once per call; per layer:
//   tmp16 = BNReLU(h) @ W[l]  (fp32 GEMM, A-staging applies prev BN; OUTPUT fp16)
//   h     = A_hat * tmp16 + b (wave gather: 2 edges/load (8B lanes), 16-edge batches)
// h stays PRE-BN fp32; consumers (next gemm, pool) apply scale/shift+relu on the fly.

#define DIM 128
#define NGRAPH 512
#define EPSV 1e-5f

// ---------------- preprocessing ----------------

__global__ __launch_bounds__(256) void k_count(const int* __restrict__ ei, int* __restrict__ cnt, int E) {
  int e = blockIdx.x * 256 + threadIdx.x;
  if (e < E) atomicAdd(&cnt[ei[E + e]], 1);
}

__global__ __launch_bounds__(512) void k_blocksum(const int* __restrict__ cnt, int* __restrict__ partial, int N) {
  __shared__ int sd[512];
  int idx = blockIdx.x * 512 + threadIdx.x;
  int v = (idx < N) ? cnt[idx] : 0;
  sd[threadIdx.x] = v;
  __syncthreads();
  for (int ofs = 256; ofs > 0; ofs >>= 1) {
    if (threadIdx.x < ofs) sd[threadIdx.x] += sd[threadIdx.x + ofs];
    __syncthreads();
  }
  if (threadIdx.x == 0) partial[blockIdx.x] = sd[0];
}

__global__ __launch_bounds__(128) void k_scanpartials(int* __restrict__ partial, int nb) {
  __shared__ int sp[128];
  int t = threadIdx.x;
  int v = (t < nb) ? partial[t] : 0;
  sp[t] = v;
  __syncthreads();
  for (int ofs = 1; ofs < 128; ofs <<= 1) {
    int a = (t >= ofs) ? sp[t - ofs] : 0;
    __syncthreads();
    sp[t] += a;
    __syncthreads();
  }
  if (t < nb) partial[t] = sp[t] - v;  // exclusive block offsets
}

__global__ __launch_bounds__(512) void k_scan_write(const int* __restrict__ cnt, const int* __restrict__ partial,
                                                    int* __restrict__ rowptr, float* __restrict__ dinv, int N) {
  __shared__ int sd[512];
  int tid = threadIdx.x;
  int idx = blockIdx.x * 512 + tid;
  int v = (idx < N) ? cnt[idx] : 0;
  sd[tid] = v;
  __syncthreads();
  for (int ofs = 1; ofs < 512; ofs <<= 1) {
    int a = (tid >= ofs) ? sd[tid - ofs] : 0;
    __syncthreads();
    sd[tid] += a;
    __syncthreads();
  }
  if (idx < N) {
    int excl = partial[blockIdx.x] + sd[tid] - v;
    rowptr[idx] = excl;
    dinv[idx] = rsqrtf((float)(v + 1));  // +1 for self loop
    if (idx == N - 1) rowptr[N] = excl + v;
  }
}

__global__ __launch_bounds__(256) void k_fill(const int* __restrict__ ei, const int* __restrict__ rowptr,
                                              int* __restrict__ cursor, const float* __restrict__ dinv,
                                              int2* __restrict__ edges, int E) {
  int e = blockIdx.x * 256 + threadIdx.x;
  if (e >= E) return;
  int s = ei[e];
  int d = ei[E + e];
  int pos = rowptr[d] + atomicAdd(&cursor[d], 1);
  edges[pos] = make_int2(s, __float_as_int(dinv[s] * dinv[d]));
}

__global__ __launch_bounds__(256) void k_gstart(const int* __restrict__ batch, int* __restrict__ start, int N) {
  int i = blockIdx.x * 256 + threadIdx.x;
  if (i >= N) return;
  int bi = batch[i];
  int prev = (i == 0) ? -1 : batch[i - 1];
  for (int g = prev + 1; g <= bi; ++g) start[g] = i;
  if (i == N - 1) {
    for (int g = bi + 1; g <= NGRAPH; ++g) start[g] = N;
  }
}

__global__ __launch_bounds__(512) void k_invcnt(const int* __restrict__ start, float* __restrict__ invcnt) {
  int g = threadIdx.x;
  if (g < NGRAPH) {
    int c = start[g + 1] - start[g];
    invcnt[g] = 1.0f / (float)max(c, 1);
  }
}

// ---------------- per-layer kernels ----------------

__device__ inline void fma4(float4& ar, float a, const float4& wv) {
  ar.x = fmaf(a, wv.x, ar.x);
  ar.y = fmaf(a, wv.y, ar.y);
  ar.z = fmaf(a, wv.z, ar.z);
  ar.w = fmaf(a, wv.w, ar.w);
}

__device__ inline float4 h4_to_f4(uint2 u) {
  float2 lo = __half22float2(*(__half2*)&u.x);
  float2 hi = __half22float2(*(__half2*)&u.y);
  return make_float4(lo.x, lo.y, hi.x, hi.y);
}

// tmp16[32 x 128] = act(A[32 x 128]) @ W[128 x 128], stored fp16.
// act = relu(sc*a+sh) if scsh, else identity. W read straight from global (L1/L2-hot).
// Block 0 also zeroes the BN-stat accumulators (stats[0..255]).
__global__ __launch_bounds__(256) void k_gemm(const float* __restrict__ A, const float* __restrict__ Wl,
                                              const float* __restrict__ scsh,  // stats+256 | nullptr
                                              __half* __restrict__ out, float* __restrict__ stats, int N) {
  __shared__ float sH[32][DIM];
  int tid = threadIdx.x;
  if (blockIdx.x == 0) stats[tid] = 0.f;  // colsum[128], colsumsq[128]
  int row0 = blockIdx.x * 32;
#pragma unroll
  for (int i = 0; i < 4; ++i) {
    int fi = tid + i * 256;  // 0..1023 float4 slots, 32 per row
    int r = fi >> 5, c4 = fi & 31;
    int row = row0 + r;
    float4 v = make_float4(0.f, 0.f, 0.f, 0.f);
    if (row < N) v = ((const float4*)(A + (size_t)row * DIM))[c4];
    if (scsh) {
      float4 sc = ((const float4*)scsh)[c4];
      float4 sh = ((const float4*)(scsh + DIM))[c4];
      v.x = fmaxf(fmaf(v.x, sc.x, sh.x), 0.f);
      v.y = fmaxf(fmaf(v.y, sc.y, sh.y), 0.f);
      v.z = fmaxf(fmaf(v.z, sc.z, sh.z), 0.f);
      v.w = fmaxf(fmaf(v.w, sc.w, sh.w), 0.f);
    }
    ((float4*)&sH[r][0])[c4] = v;
  }
  __syncthreads();
  int ct = tid & 31, rt = tid >> 5;  // 32 col-threads x 8 row-threads
  const float4* Wv = (const float4*)Wl;  // row k -> Wv[k*32 + ct]
  float4 acc[4];
#pragma unroll
  for (int r = 0; r < 4; ++r) acc[r] = make_float4(0.f, 0.f, 0.f, 0.f);
  for (int k4 = 0; k4 < 32; ++k4) {
    float4 wv0 = Wv[(4 * k4 + 0) * 32 + ct];
    float4 wv1 = Wv[(4 * k4 + 1) * 32 + ct];
    float4 wv2 = Wv[(4 * k4 + 2) * 32 + ct];
    float4 wv3 = Wv[(4 * k4 + 3) * 32 + ct];
#pragma unroll
    for (int r = 0; r < 4; ++r) {
      float4 av = *(const float4*)&sH[rt + 8 * r][4 * k4];
      fma4(acc[r], av.x, wv0);
      fma4(acc[r], av.y, wv1);
      fma4(acc[r], av.z, wv2);
      fma4(acc[r], av.w, wv3);
    }
  }
#pragma unroll
  for (int r = 0; r < 4; ++r) {
    int row = row0 + rt + 8 * r;
    if (row < N) {
      __half2 h0 = __floats2half2_rn(acc[r].x, acc[r].y);
      __half2 h1 = __floats2half2_rn(acc[r].z, acc[r].w);
      uint2 packed = make_uint2(*(unsigned int*)&h0, *(unsigned int*)&h1);
      *(uint2*)(out + (size_t)row * DIM + 4 * ct) = packed;
    }
  }
}

// h[i] = sum_e val_e * tmp16[col_e] + dinv[i]^2 * tmp16[i] + b; BN-stat accumulation fused.
// 2 edges per wave-load: lanes 0-31 = edge A cols, lanes 32-63 = edge B cols (8B/lane).
// 16-edge batches (8 loads x 512B in flight); zero-padded slots gather row 0 (L2-hot).
__global__ __launch_bounds__(256) void k_agg(const __half* __restrict__ tmp16, const int* __restrict__ rowptr,
                                             const int2* __restrict__ edges, const float* __restrict__ dinv,
                                             const float* __restrict__ bias, float* __restrict__ hout,
                                             float* __restrict__ stats, int N) {
  const uint2* __restrict__ T2 = (const uint2*)tmp16;  // row i -> T2[i*32 + c], c = col group (4 cols)
  int lane = threadIdx.x & 63;
  int wid = threadIdx.x >> 6;
  int hw = lane >> 5;       // 0: edge A, 1: edge B
  int c = lane & 31;        // col group: columns 4c..4c+3
  int gwave = blockIdx.x * 4 + wid;
  int nwaves = gridDim.x * 4;
  float4 bias4 = ((const float4*)bias)[c];
  float4 sum4 = make_float4(0.f, 0.f, 0.f, 0.f);
  float4 sq4 = make_float4(0.f, 0.f, 0.f, 0.f);
  for (int i = gwave; i < N; i += nwaves) {
    float4 acc4 = make_float4(0.f, 0.f, 0.f, 0.f);
    if (hw == 0) {  // self term once
      float di = dinv[i];
      float self = di * di;
      float4 t = h4_to_f4(T2[(size_t)i * 32 + c]);
      acc4.x = self * t.x;
      acc4.y = self * t.y;
      acc4.z = self * t.z;
      acc4.w = self * t.w;
    }
    int beg = rowptr[i], end = rowptr[i + 1];
    for (int e0 = beg; e0 < end; e0 += 64) {
      int e = e0 + lane;
      int s = 0;
      float v = 0.f;
      if (e < end) {
        int2 ev = edges[e];
        s = ev.x;
        v = __int_as_float(ev.y);
      }
      int m = min(64, end - e0);
      for (int j = 0; j < m; j += 16) {
        uint2 uu[8];
        float vv[8];
#pragma unroll
        for (int q = 0; q < 8; ++q) {
          int idx = j + 2 * q + hw;
          int sj = __shfl(s, idx);
          vv[q] = __shfl(v, idx);
          uu[q] = T2[(size_t)sj * 32 + c];
        }
#pragma unroll
        for (int q = 0; q < 8; ++q) {
          float4 t = h4_to_f4(uu[q]);
          acc4.x = fmaf(vv[q], t.x, acc4.x);
          acc4.y = fmaf(vv[q], t.y, acc4.y);
          acc4.z = fmaf(vv[q], t.z, acc4.z);
          acc4.w = fmaf(vv[q], t.w, acc4.w);
        }
      }
    }
    // combine the two half-wave partials (lane ^ 32 holds the other edges' sum)
    acc4.x += __shfl_xor(acc4.x, 32);
    acc4.y += __shfl_xor(acc4.y, 32);
    acc4.z += __shfl_xor(acc4.z, 32);
    acc4.w += __shfl_xor(acc4.w, 32);
    acc4.x += bias4.x;
    acc4.y += bias4.y;
    acc4.z += bias4.z;
    acc4.w += bias4.w;
    if (hw == 0) {
      *(float4*)(hout + (size_t)i * DIM + 4 * c) = acc4;
      sum4.x += acc4.x;
      sum4.y += acc4.y;
      sum4.z += acc4.z;
      sum4.w += acc4.w;
      sq4.x = fmaf(acc4.x, acc4.x, sq4.x);
      sq4.y = fmaf(acc4.y, acc4.y, sq4.y);
      sq4.z = fmaf(acc4.z, acc4.z, sq4.z);
      sq4.w = fmaf(acc4.w, acc4.w, sq4.w);
    }
  }
  __shared__ float red[256][8];
  red[threadIdx.x][0] = sum4.x;
  red[threadIdx.x][1] = sum4.y;
  red[threadIdx.x][2] = sum4.z;
  red[threadIdx.x][3] = sum4.w;
  red[threadIdx.x][4] = sq4.x;
  red[threadIdx.x][5] = sq4.y;
  red[threadIdx.x][6] = sq4.z;
  red[threadIdx.x][7] = sq4.w;
  __syncthreads();
  if (threadIdx.x < 32) {
    int cg = threadIdx.x;  // col group
    float a[8];
#pragma unroll
    for (int k = 0; k < 8; ++k)
      a[k] = red[cg][k] + red[64 + cg][k] + red[128 + cg][k] + red[192 + cg][k];
#pragma unroll
    for (int k = 0; k < 4; ++k) {
      atomicAdd(&stats[4 * cg + k], a[k]);
      atomicAdd(&stats[DIM + 4 * cg + k], a[4 + k]);
    }
  }
}

__global__ __launch_bounds__(128) void k_bnstat(float* __restrict__ stats, const float* __restrict__ gamma,
                                                const float* __restrict__ beta, int N) {
  int c = threadIdx.x;
  float invN = 1.f / (float)N;
  float mu = stats[c] * invN;
  float var = stats[DIM + c] * invN - mu * mu;
  float rstd = rsqrtf(var + EPSV);
  float sc = gamma[c] * rstd;
  stats[2 * DIM + c] = sc;
  stats[3 * DIM + c] = beta[c] - mu * sc;
}

// pool mean of relu(sc*h+sh) per graph
__global__ __launch_bounds__(512) void k_pool(const float* __restrict__ h, const int* __restrict__ start,
                                              const float* __restrict__ invcnt, const float* __restrict__ scsh,
                                              float* __restrict__ pooled, int level) {
  int g = blockIdx.x;
  int s = start[g], e = start[g + 1];
  int c = threadIdx.x & 127;
  int stripe = threadIdx.x >> 7;  // 0..3
  float sc = scsh[c], sh = scsh[DIM + c];
  float acc = 0.f;
  for (int r = s + stripe; r < e; r += 4) acc += fmaxf(fmaf(h[(size_t)r * DIM + c], sc, sh), 0.f);
  __shared__ float red[4][DIM];
  red[stripe][c] = acc;
  __syncthreads();
  if (threadIdx.x < DIM) {
    float v = (red[0][c] + red[1][c] + red[2][c] + red[3][c]) * invcnt[g];
    pooled[(size_t)g * (3 * DIM) + level * DIM + c] = v;
  }
}

__global__ __launch_bounds__(512) void k_final(const float* __restrict__ pooled, const float* __restrict__ Wf,
                                               const float* __restrict__ bf, float* __restrict__ out) {
  int t = blockIdx.x * 512 + threadIdx.x;
  if (t >= NGRAPH * DIM) return;
  int j = t & (DIM - 1);
  int i = t >> 7;
  const float* prow = pooled + (size_t)i * (3 * DIM);
  float acc = bf[j];
  for (int k = 0; k < 3 * DIM; ++k) acc = fmaf(prow[k], Wf[(size_t)k * DIM + j], acc);
  out[t] = fmaxf(acc, 0.f);
}

// ---------------- launcher ----------------

extern "C" void kernel_launch(void* const* d_in, const int* in_sizes, int n_in,
                              void* d_out, int out_size, void* d_ws, size_t ws_size,
                              hipStream_t stream) {
  const float* x = (const float*)d_in[0];
  const int* ei = (const int*)d_in[1];
  const int* batch = (const int*)d_in[2];
  const float* W = (const float*)d_in[3];
  const float* b = (const float*)d_in[4];
  const float* gamma = (const float*)d_in[5];
  const float* beta = (const float*)d_in[6];
  const float* Wf = (const float*)d_in[7];
  const float* bf = (const float*)d_in[8];
  float* out = (float*)d_out;

  const int N = in_sizes[0] / DIM;   // 50000
  const int E = in_sizes[1] / 2;     // 800000

  char* base = (char*)d_ws;
  size_t off = 0;
  auto alloc = [&](size_t bytes) -> char* {
    char* p = base + off;
    off += (bytes + 255) & ~(size_t)255;
    return p;
  };
  float* h      = (float*)alloc((size_t)N * DIM * 4);
  __half* tmp16 = (__half*)alloc((size_t)N * DIM * 2);
  int* cnt      = (int*)alloc((size_t)N * 4);
  int* cursor   = (int*)alloc((size_t)N * 4);
  int* rowptr   = (int*)alloc((size_t)(N + 1) * 4);
  int* partial  = (int*)alloc(256 * 4);
  float* dinv   = (float*)alloc((size_t)N * 4);
  int2* edges   = (int2*)alloc((size_t)E * 8);
  float* stats  = (float*)alloc(4 * DIM * 4);  // colsum|colsumsq|scale|shift
  int* start    = (int*)alloc((NGRAPH + 1) * 4);
  float* invcnt = (float*)alloc(NGRAPH * 4);
  float* pooled = (float*)alloc((size_t)NGRAPH * 3 * DIM * 4);
  (void)ws_size;

  (void)hipMemsetAsync(cnt, 0, (size_t)N * 4, stream);
  (void)hipMemsetAsync(cursor, 0, (size_t)N * 4, stream);

  int nbScan = (N + 511) / 512;  // 98
  k_count<<<(E + 255) / 256, 256, 0, stream>>>(ei, cnt, E);
  k_blocksum<<<nbScan, 512, 0, stream>>>(cnt, partial, N);
  k_scanpartials<<<1, 128, 0, stream>>>(partial, nbScan);
  k_scan_write<<<nbScan, 512, 0, stream>>>(cnt, partial, rowptr, dinv, N);
  k_fill<<<(E + 255) / 256, 256, 0, stream>>>(ei, rowptr, cursor, dinv, edges, E);
  k_gstart<<<(N + 255) / 256, 256, 0, stream>>>(batch, start, N);
  k_invcnt<<<1, 512, 0, stream>>>(start, invcnt);

  int gemmGrid = (N + 31) / 32;
  for (int l = 0; l < 6; ++l) {
    const float* hin = (l == 0) ? x : h;
    const float* scsh = (l == 0) ? nullptr : stats + 2 * DIM;
    k_gemm<<<gemmGrid, 256, 0, stream>>>(hin, W + (size_t)l * DIM * DIM, scsh, tmp16, stats, N);
    k_agg<<<2048, 256, 0, stream>>>(tmp16, rowptr, edges, dinv, b + (size_t)l * DIM, h, stats, N);
    k_bnstat<<<1, 128, 0, stream>>>(stats, gamma + (size_t)l * DIM, beta + (size_t)l * DIM, N);
    if (l & 1) k_pool<<<NGRAPH, 512, 0, stream>>>(h, start, invcnt, stats + 2 * DIM, pooled, l >> 1);
  }
  k_final<<<(NGRAPH * DIM + 511) / 512, 512, 0, stream>>>(pooled, Wf, bf, out);
}

// Round 7
// 1164.146 us; speedup vs baseline: 1.5015x; 1.5015x over previous
//
#include <hip/hip_runtime.h>
#include <hip/hip_fp16.h>

// HierarchicalEncoder: 6× (GCN -> BN -> ReLU) with level pooling + final linear.
// dst-CSR built once per call; per layer:
//   tmp16 = BNReLU(h) @ W[l]  (fp32 GEMM, A-staging applies prev BN; OUTPUT fp16)
//   h     = A_hat * tmp16 + b (wave-per-node gather; scalar edge loads; 16 gathers in flight)
// h stays PRE-BN fp32; consumers (next gemm, pool) apply scale/shift+relu on the fly.

#define DIM 128
#define NGRAPH 512
#define EPSV 1e-5f

// ---------------- preprocessing ----------------

__global__ __launch_bounds__(256) void k_count(const int* __restrict__ ei, int* __restrict__ cnt, int E) {
  int e = blockIdx.x * 256 + threadIdx.x;
  if (e < E) atomicAdd(&cnt[ei[E + e]], 1);
}

__global__ __launch_bounds__(512) void k_blocksum(const int* __restrict__ cnt, int* __restrict__ partial, int N) {
  __shared__ int sd[512];
  int idx = blockIdx.x * 512 + threadIdx.x;
  int v = (idx < N) ? cnt[idx] : 0;
  sd[threadIdx.x] = v;
  __syncthreads();
  for (int ofs = 256; ofs > 0; ofs >>= 1) {
    if (threadIdx.x < ofs) sd[threadIdx.x] += sd[threadIdx.x + ofs];
    __syncthreads();
  }
  if (threadIdx.x == 0) partial[blockIdx.x] = sd[0];
}

__global__ __launch_bounds__(128) void k_scanpartials(int* __restrict__ partial, int nb) {
  __shared__ int sp[128];
  int t = threadIdx.x;
  int v = (t < nb) ? partial[t] : 0;
  sp[t] = v;
  __syncthreads();
  for (int ofs = 1; ofs < 128; ofs <<= 1) {
    int a = (t >= ofs) ? sp[t - ofs] : 0;
    __syncthreads();
    sp[t] += a;
    __syncthreads();
  }
  if (t < nb) partial[t] = sp[t] - v;  // exclusive block offsets
}

__global__ __launch_bounds__(512) void k_scan_write(const int* __restrict__ cnt, const int* __restrict__ partial,
                                                    int* __restrict__ rowptr, float* __restrict__ dinv, int N) {
  __shared__ int sd[512];
  int tid = threadIdx.x;
  int idx = blockIdx.x * 512 + tid;
  int v = (idx < N) ? cnt[idx] : 0;
  sd[tid] = v;
  __syncthreads();
  for (int ofs = 1; ofs < 512; ofs <<= 1) {
    int a = (tid >= ofs) ? sd[tid - ofs] : 0;
    __syncthreads();
    sd[tid] += a;
    __syncthreads();
  }
  if (idx < N) {
    int excl = partial[blockIdx.x] + sd[tid] - v;
    rowptr[idx] = excl;
    dinv[idx] = rsqrtf((float)(v + 1));  // +1 for self loop
    if (idx == N - 1) rowptr[N] = excl + v;
  }
}

__global__ __launch_bounds__(256) void k_fill(const int* __restrict__ ei, const int* __restrict__ rowptr,
                                              int* __restrict__ cursor, const float* __restrict__ dinv,
                                              int2* __restrict__ edges, int E) {
  int e = blockIdx.x * 256 + threadIdx.x;
  if (e >= E) return;
  int s = ei[e];
  int d = ei[E + e];
  int pos = rowptr[d] + atomicAdd(&cursor[d], 1);
  edges[pos] = make_int2(s, __float_as_int(dinv[s] * dinv[d]));
}

__global__ __launch_bounds__(256) void k_gstart(const int* __restrict__ batch, int* __restrict__ start, int N) {
  int i = blockIdx.x * 256 + threadIdx.x;
  if (i >= N) return;
  int bi = batch[i];
  int prev = (i == 0) ? -1 : batch[i - 1];
  for (int g = prev + 1; g <= bi; ++g) start[g] = i;
  if (i == N - 1) {
    for (int g = bi + 1; g <= NGRAPH; ++g) start[g] = N;
  }
}

__global__ __launch_bounds__(512) void k_invcnt(const int* __restrict__ start, float* __restrict__ invcnt) {
  int g = threadIdx.x;
  if (g < NGRAPH) {
    int c = start[g + 1] - start[g];
    invcnt[g] = 1.0f / (float)max(c, 1);
  }
}

// ---------------- per-layer kernels ----------------

__device__ inline void fma4(float4& ar, float a, const float4& wv) {
  ar.x = fmaf(a, wv.x, ar.x);
  ar.y = fmaf(a, wv.y, ar.y);
  ar.z = fmaf(a, wv.z, ar.z);
  ar.w = fmaf(a, wv.w, ar.w);
}

// tmp16[32 x 128] = act(A[32 x 128]) @ W[128 x 128], stored fp16.
// act = relu(sc*a+sh) if scsh, else identity. W read straight from global (L1/L2-hot).
// Block 0 also zeroes the BN-stat accumulators (stats[0..255]).
__global__ __launch_bounds__(256) void k_gemm(const float* __restrict__ A, const float* __restrict__ Wl,
                                              const float* __restrict__ scsh,  // stats+256 | nullptr
                                              __half* __restrict__ out, float* __restrict__ stats, int N) {
  __shared__ float sH[32][DIM];
  int tid = threadIdx.x;
  if (blockIdx.x == 0) stats[tid] = 0.f;  // colsum[128], colsumsq[128]
  int row0 = blockIdx.x * 32;
#pragma unroll
  for (int i = 0; i < 4; ++i) {
    int fi = tid + i * 256;  // 0..1023 float4 slots, 32 per row
    int r = fi >> 5, c4 = fi & 31;
    int row = row0 + r;
    float4 v = make_float4(0.f, 0.f, 0.f, 0.f);
    if (row < N) v = ((const float4*)(A + (size_t)row * DIM))[c4];
    if (scsh) {
      float4 sc = ((const float4*)scsh)[c4];
      float4 sh = ((const float4*)(scsh + DIM))[c4];
      v.x = fmaxf(fmaf(v.x, sc.x, sh.x), 0.f);
      v.y = fmaxf(fmaf(v.y, sc.y, sh.y), 0.f);
      v.z = fmaxf(fmaf(v.z, sc.z, sh.z), 0.f);
      v.w = fmaxf(fmaf(v.w, sc.w, sh.w), 0.f);
    }
    ((float4*)&sH[r][0])[c4] = v;
  }
  __syncthreads();
  int ct = tid & 31, rt = tid >> 5;  // 32 col-threads x 8 row-threads
  const float4* Wv = (const float4*)Wl;  // row k -> Wv[k*32 + ct]
  float4 acc[4];
#pragma unroll
  for (int r = 0; r < 4; ++r) acc[r] = make_float4(0.f, 0.f, 0.f, 0.f);
  for (int k4 = 0; k4 < 32; ++k4) {
    float4 wv0 = Wv[(4 * k4 + 0) * 32 + ct];
    float4 wv1 = Wv[(4 * k4 + 1) * 32 + ct];
    float4 wv2 = Wv[(4 * k4 + 2) * 32 + ct];
    float4 wv3 = Wv[(4 * k4 + 3) * 32 + ct];
#pragma unroll
    for (int r = 0; r < 4; ++r) {
      float4 av = *(const float4*)&sH[rt + 8 * r][4 * k4];
      fma4(acc[r], av.x, wv0);
      fma4(acc[r], av.y, wv1);
      fma4(acc[r], av.z, wv2);
      fma4(acc[r], av.w, wv3);
    }
  }
#pragma unroll
  for (int r = 0; r < 4; ++r) {
    int row = row0 + rt + 8 * r;
    if (row < N) {
      __half2 h0 = __floats2half2_rn(acc[r].x, acc[r].y);
      __half2 h1 = __floats2half2_rn(acc[r].z, acc[r].w);
      uint2 packed = make_uint2(*(unsigned int*)&h0, *(unsigned int*)&h1);
      *(uint2*)(out + (size_t)row * DIM + 4 * ct) = packed;
    }
  }
}

// h[i] = sum_e val_e * tmp16[col_e] + dinv[i]^2 * tmp16[i] + b; BN-stat accumulation fused.
// One row per wave-load (fully coalesced 256B). Edge metadata is wave-uniform -> scalar
// (s_load) path, no shuffles. 16 gathers in flight; overshoot batches masked by uniform
// cselect (masked lanes gather row 0, L1-hot). edges alloc is padded by 16 entries.
__global__ __launch_bounds__(256) void k_agg(const __half* __restrict__ tmp16, const int* __restrict__ rowptr,
                                             const int2* __restrict__ edges, const float* __restrict__ dinv,
                                             const float* __restrict__ bias, float* __restrict__ hout,
                                             float* __restrict__ stats, int N) {
  const unsigned int* __restrict__ T = (const unsigned int*)tmp16;  // half2 slots; row i -> T[i*64 + lane]
  int lane = threadIdx.x & 63;
  int wslot = __builtin_amdgcn_readfirstlane(threadIdx.x >> 6);  // wave-uniform in SGPR
  int gwave = blockIdx.x * 4 + wslot;
  int nwaves = gridDim.x * 4;
  float bx = bias[2 * lane], by = bias[2 * lane + 1];
  float sum0 = 0.f, sum1 = 0.f, sq0 = 0.f, sq1 = 0.f;
  for (int i = gwave; i < N; i += nwaves) {
    float di = dinv[i];
    float self = di * di;
    unsigned int u0 = T[(size_t)i * 64 + lane];
    float2 t0 = __half22float2(*(__half2*)&u0);
    float ax0 = self * t0.x, ay0 = self * t0.y;
    float ax1 = 0.f, ay1 = 0.f;
    int beg = rowptr[i], end = rowptr[i + 1];
    for (int e0 = beg; e0 < end; e0 += 16) {
      int sidx[16];
      float vval[16];
#pragma unroll
      for (int q = 0; q < 16; ++q) {
        int2 ev = edges[e0 + q];  // uniform address -> s_load; may overshoot (masked below)
        bool ok = (e0 + q) < end;
        sidx[q] = ok ? ev.x : 0;
        vval[q] = ok ? __int_as_float(ev.y) : 0.f;
      }
      unsigned int uu[16];
#pragma unroll
      for (int q = 0; q < 16; ++q) uu[q] = T[(size_t)sidx[q] * 64 + lane];
#pragma unroll
      for (int q = 0; q < 16; q += 2) {
        float2 ta = __half22float2(*(__half2*)&uu[q]);
        float2 tb = __half22float2(*(__half2*)&uu[q + 1]);
        ax0 = fmaf(vval[q], ta.x, ax0);
        ay0 = fmaf(vval[q], ta.y, ay0);
        ax1 = fmaf(vval[q + 1], tb.x, ax1);
        ay1 = fmaf(vval[q + 1], tb.y, ay1);
      }
    }
    float ax = ax0 + ax1 + bx;
    float ay = ay0 + ay1 + by;
    ((float2*)(hout + (size_t)i * DIM))[lane] = make_float2(ax, ay);
    sum0 += ax;
    sum1 += ay;
    sq0 = fmaf(ax, ax, sq0);
    sq1 = fmaf(ay, ay, sq1);
  }
  __shared__ float red[256][4];
  red[threadIdx.x][0] = sum0;
  red[threadIdx.x][1] = sum1;
  red[threadIdx.x][2] = sq0;
  red[threadIdx.x][3] = sq1;
  __syncthreads();
  if (threadIdx.x < 64) {
    int l = threadIdx.x;
    float a0 = red[l][0] + red[64 + l][0] + red[128 + l][0] + red[192 + l][0];
    float a1 = red[l][1] + red[64 + l][1] + red[128 + l][1] + red[192 + l][1];
    float q0 = red[l][2] + red[64 + l][2] + red[128 + l][2] + red[192 + l][2];
    float q1 = red[l][3] + red[64 + l][3] + red[128 + l][3] + red[192 + l][3];
    atomicAdd(&stats[2 * l], a0);
    atomicAdd(&stats[2 * l + 1], a1);
    atomicAdd(&stats[DIM + 2 * l], q0);
    atomicAdd(&stats[DIM + 2 * l + 1], q1);
  }
}

__global__ __launch_bounds__(128) void k_bnstat(float* __restrict__ stats, const float* __restrict__ gamma,
                                                const float* __restrict__ beta, int N) {
  int c = threadIdx.x;
  float invN = 1.f / (float)N;
  float mu = stats[c] * invN;
  float var = stats[DIM + c] * invN - mu * mu;
  float rstd = rsqrtf(var + EPSV);
  float sc = gamma[c] * rstd;
  stats[2 * DIM + c] = sc;
  stats[3 * DIM + c] = beta[c] - mu * sc;
}

// pool mean of relu(sc*h+sh) per graph
__global__ __launch_bounds__(512) void k_pool(const float* __restrict__ h, const int* __restrict__ start,
                                              const float* __restrict__ invcnt, const float* __restrict__ scsh,
                                              float* __restrict__ pooled, int level) {
  int g = blockIdx.x;
  int s = start[g], e = start[g + 1];
  int c = threadIdx.x & 127;
  int stripe = threadIdx.x >> 7;  // 0..3
  float sc = scsh[c], sh = scsh[DIM + c];
  float acc = 0.f;
  for (int r = s + stripe; r < e; r += 4) acc += fmaxf(fmaf(h[(size_t)r * DIM + c], sc, sh), 0.f);
  __shared__ float red[4][DIM];
  red[stripe][c] = acc;
  __syncthreads();
  if (threadIdx.x < DIM) {
    float v = (red[0][c] + red[1][c] + red[2][c] + red[3][c]) * invcnt[g];
    pooled[(size_t)g * (3 * DIM) + level * DIM + c] = v;
  }
}

__global__ __launch_bounds__(512) void k_final(const float* __restrict__ pooled, const float* __restrict__ Wf,
                                               const float* __restrict__ bf, float* __restrict__ out) {
  int t = blockIdx.x * 512 + threadIdx.x;
  if (t >= NGRAPH * DIM) return;
  int j = t & (DIM - 1);
  int i = t >> 7;
  const float* prow = pooled + (size_t)i * (3 * DIM);
  float acc = bf[j];
  for (int k = 0; k < 3 * DIM; ++k) acc = fmaf(prow[k], Wf[(size_t)k * DIM + j], acc);
  out[t] = fmaxf(acc, 0.f);
}

// ---------------- launcher ----------------

extern "C" void kernel_launch(void* const* d_in, const int* in_sizes, int n_in,
                              void* d_out, int out_size, void* d_ws, size_t ws_size,
                              hipStream_t stream) {
  const float* x = (const float*)d_in[0];
  const int* ei = (const int*)d_in[1];
  const int* batch = (const int*)d_in[2];
  const float* W = (const float*)d_in[3];
  const float* b = (const float*)d_in[4];
  const float* gamma = (const float*)d_in[5];
  const float* beta = (const float*)d_in[6];
  const float* Wf = (const float*)d_in[7];
  const float* bf = (const float*)d_in[8];
  float* out = (float*)d_out;

  const int N = in_sizes[0] / DIM;   // 50000
  const int E = in_sizes[1] / 2;     // 800000

  char* base = (char*)d_ws;
  size_t off = 0;
  auto alloc = [&](size_t bytes) -> char* {
    char* p = base + off;
    off += (bytes + 255) & ~(size_t)255;
    return p;
  };
  float* h      = (float*)alloc((size_t)N * DIM * 4);
  __half* tmp16 = (__half*)alloc((size_t)N * DIM * 2);
  int* cnt      = (int*)alloc((size_t)N * 4);
  int* cursor   = (int*)alloc((size_t)N * 4);
  int* rowptr   = (int*)alloc((size_t)(N + 1) * 4);
  int* partial  = (int*)alloc(256 * 4);
  float* dinv   = (float*)alloc((size_t)N * 4);
  int2* edges   = (int2*)alloc((size_t)(E + 16) * 8);  // +16 pad for overshoot batches
  float* stats  = (float*)alloc(4 * DIM * 4);  // colsum|colsumsq|scale|shift
  int* start    = (int*)alloc((NGRAPH + 1) * 4);
  float* invcnt = (float*)alloc(NGRAPH * 4);
  float* pooled = (float*)alloc((size_t)NGRAPH * 3 * DIM * 4);
  (void)ws_size;

  (void)hipMemsetAsync(cnt, 0, (size_t)N * 4, stream);
  (void)hipMemsetAsync(cursor, 0, (size_t)N * 4, stream);

  int nbScan = (N + 511) / 512;  // 98
  k_count<<<(E + 255) / 256, 256, 0, stream>>>(ei, cnt, E);
  k_blocksum<<<nbScan, 512, 0, stream>>>(cnt, partial, N);
  k_scanpartials<<<1, 128, 0, stream>>>(partial, nbScan);
  k_scan_write<<<nbScan, 512, 0, stream>>>(cnt, partial, rowptr, dinv, N);
  k_fill<<<(E + 255) / 256, 256, 0, stream>>>(ei, rowptr, cursor, dinv, edges, E);
  k_gstart<<<(N + 255) / 256, 256, 0, stream>>>(batch, start, N);
  k_invcnt<<<1, 512, 0, stream>>>(start, invcnt);

  int gemmGrid = (N + 31) / 32;
  for (int l = 0; l < 6; ++l) {
    const float* hin = (l == 0) ? x : h;
    const float* scsh = (l == 0) ? nullptr : stats + 2 * DIM;
    k_gemm<<<gemmGrid, 256, 0, stream>>>(hin, W + (size_t)l * DIM * DIM, scsh, tmp16, stats, N);
    k_agg<<<2048, 256, 0, stream>>>(tmp16, rowptr, edges, dinv, b + (size_t)l * DIM, h, stats, N);
    k_bnstat<<<1, 128, 0, stream>>>(stats, gamma + (size_t)l * DIM, beta + (size_t)l * DIM, N);
    if (l & 1) k_pool<<<NGRAPH, 512, 0, stream>>>(h, start, invcnt, stats + 2 * DIM, pooled, l >> 1);
  }
  k_final<<<(NGRAPH * DIM + 511) / 512, 512, 0, stream>>>(pooled, Wf, bf, out);
}

// Round 9
// 883.584 us; speedup vs baseline: 1.9782x; 1.3175x over previous
//
#include <hip/hip_runtime.h>
#include <hip/hip_fp16.h>

// HierarchicalEncoder: 6× (GCN -> BN -> ReLU) with level pooling + final linear.
// dst-CSR built once per call; per layer:
//   tmp16 = BNReLU(h) @ W[l]   (fp32 GEMM; output fp16 in 4 column PANELS of 32 cols)
//   h     = A_hat * tmp16 + b  (phase-per-XCD-pair gather: each XCD touches one 3.2MB
//                               panel -> L2-resident; 4 edges x 16 slots per gather)
// h stays PRE-BN fp32; consumers (next gemm, pool) apply scale/shift+relu on the fly.

#define DIM 128
#define NGRAPH 512
#define EPSV 1e-5f

// ---------------- preprocessing ----------------

__global__ __launch_bounds__(256) void k_count(const int* __restrict__ ei, int* __restrict__ cnt, int E) {
  int e = blockIdx.x * 256 + threadIdx.x;
  if (e < E) atomicAdd(&cnt[ei[E + e]], 1);
}

__global__ __launch_bounds__(512) void k_blocksum(const int* __restrict__ cnt, int* __restrict__ partial, int N) {
  __shared__ int sd[512];
  int idx = blockIdx.x * 512 + threadIdx.x;
  int v = (idx < N) ? cnt[idx] : 0;
  sd[threadIdx.x] = v;
  __syncthreads();
  for (int ofs = 256; ofs > 0; ofs >>= 1) {
    if (threadIdx.x < ofs) sd[threadIdx.x] += sd[threadIdx.x + ofs];
    __syncthreads();
  }
  if (threadIdx.x == 0) partial[blockIdx.x] = sd[0];
}

__global__ __launch_bounds__(128) void k_scanpartials(int* __restrict__ partial, int nb) {
  __shared__ int sp[128];
  int t = threadIdx.x;
  int v = (t < nb) ? partial[t] : 0;
  sp[t] = v;
  __syncthreads();
  for (int ofs = 1; ofs < 128; ofs <<= 1) {
    int a = (t >= ofs) ? sp[t - ofs] : 0;
    __syncthreads();
    sp[t] += a;
    __syncthreads();
  }
  if (t < nb) partial[t] = sp[t] - v;  // exclusive block offsets
}

__global__ __launch_bounds__(512) void k_scan_write(const int* __restrict__ cnt, const int* __restrict__ partial,
                                                    int* __restrict__ rowptr, float* __restrict__ dinv, int N) {
  __shared__ int sd[512];
  int tid = threadIdx.x;
  int idx = blockIdx.x * 512 + tid;
  int v = (idx < N) ? cnt[idx] : 0;
  sd[tid] = v;
  __syncthreads();
  for (int ofs = 1; ofs < 512; ofs <<= 1) {
    int a = (tid >= ofs) ? sd[tid - ofs] : 0;
    __syncthreads();
    sd[tid] += a;
    __syncthreads();
  }
  if (idx < N) {
    int excl = partial[blockIdx.x] + sd[tid] - v;
    rowptr[idx] = excl;
    dinv[idx] = rsqrtf((float)(v + 1));  // +1 for self loop
    if (idx == N - 1) rowptr[N] = excl + v;
  }
}

__global__ __launch_bounds__(256) void k_fill(const int* __restrict__ ei, const int* __restrict__ rowptr,
                                              int* __restrict__ cursor, const float* __restrict__ dinv,
                                              int2* __restrict__ edges, int E) {
  int e = blockIdx.x * 256 + threadIdx.x;
  if (e >= E) return;
  int s = ei[e];
  int d = ei[E + e];
  int pos = rowptr[d] + atomicAdd(&cursor[d], 1);
  edges[pos] = make_int2(s, __float_as_int(dinv[s] * dinv[d]));
}

__global__ __launch_bounds__(256) void k_gstart(const int* __restrict__ batch, int* __restrict__ start, int N) {
  int i = blockIdx.x * 256 + threadIdx.x;
  if (i >= N) return;
  int bi = batch[i];
  int prev = (i == 0) ? -1 : batch[i - 1];
  for (int g = prev + 1; g <= bi; ++g) start[g] = i;
  if (i == N - 1) {
    for (int g = bi + 1; g <= NGRAPH; ++g) start[g] = N;
  }
}

__global__ __launch_bounds__(512) void k_invcnt(const int* __restrict__ start, float* __restrict__ invcnt) {
  int g = threadIdx.x;
  if (g < NGRAPH) {
    int c = start[g + 1] - start[g];
    invcnt[g] = 1.0f / (float)max(c, 1);
  }
}

// ---------------- per-layer kernels ----------------

__device__ inline void fma4(float4& ar, float a, const float4& wv) {
  ar.x = fmaf(a, wv.x, ar.x);
  ar.y = fmaf(a, wv.y, ar.y);
  ar.z = fmaf(a, wv.z, ar.z);
  ar.w = fmaf(a, wv.w, ar.w);
}

// tmp16 = act(A) @ W, stored fp16 in 4 column panels: panel p = cols 32p..32p+31,
// laid out [N][16] u32 (half2 slots), panel stride N*16 u32.
// act = relu(sc*a+sh) if scsh, else identity. W read straight from global (L1/L2-hot).
// Block 0 also zeroes the BN-stat accumulators (stats[0..255]).
__global__ __launch_bounds__(256) void k_gemm(const float* __restrict__ A, const float* __restrict__ Wl,
                                              const float* __restrict__ scsh,  // stats+256 | nullptr
                                              unsigned int* __restrict__ T, float* __restrict__ stats, int N) {
  __shared__ float sH[32][DIM];
  int tid = threadIdx.x;
  if (blockIdx.x == 0) stats[tid] = 0.f;  // colsum[128], colsumsq[128]
  int row0 = blockIdx.x * 32;
#pragma unroll
  for (int i = 0; i < 4; ++i) {
    int fi = tid + i * 256;  // 0..1023 float4 slots, 32 per row
    int r = fi >> 5, c4 = fi & 31;
    int row = row0 + r;
    float4 v = make_float4(0.f, 0.f, 0.f, 0.f);
    if (row < N) v = ((const float4*)(A + (size_t)row * DIM))[c4];
    if (scsh) {
      float4 sc = ((const float4*)scsh)[c4];
      float4 sh = ((const float4*)(scsh + DIM))[c4];
      v.x = fmaxf(fmaf(v.x, sc.x, sh.x), 0.f);
      v.y = fmaxf(fmaf(v.y, sc.y, sh.y), 0.f);
      v.z = fmaxf(fmaf(v.z, sc.z, sh.z), 0.f);
      v.w = fmaxf(fmaf(v.w, sc.w, sh.w), 0.f);
    }
    ((float4*)&sH[r][0])[c4] = v;
  }
  __syncthreads();
  int ct = tid & 31, rt = tid >> 5;  // 32 col-threads x 8 row-threads
  const float4* Wv = (const float4*)Wl;  // row k -> Wv[k*32 + ct]
  float4 acc[4];
#pragma unroll
  for (int r = 0; r < 4; ++r) acc[r] = make_float4(0.f, 0.f, 0.f, 0.f);
  for (int k4 = 0; k4 < 32; ++k4) {
    float4 wv0 = Wv[(4 * k4 + 0) * 32 + ct];
    float4 wv1 = Wv[(4 * k4 + 1) * 32 + ct];
    float4 wv2 = Wv[(4 * k4 + 2) * 32 + ct];
    float4 wv3 = Wv[(4 * k4 + 3) * 32 + ct];
#pragma unroll
    for (int r = 0; r < 4; ++r) {
      float4 av = *(const float4*)&sH[rt + 8 * r][4 * k4];
      fma4(acc[r], av.x, wv0);
      fma4(acc[r], av.y, wv1);
      fma4(acc[r], av.z, wv2);
      fma4(acc[r], av.w, wv3);
    }
  }
  int panel = ct >> 3;          // cols 4ct..4ct+3 live in panel ct/8
  int psl = (ct & 7) * 2;       // u32 slot within panel row
  unsigned int* Tp = T + (size_t)panel * N * 16;
#pragma unroll
  for (int r = 0; r < 4; ++r) {
    int row = row0 + rt + 8 * r;
    if (row < N) {
      __half2 h0 = __floats2half2_rn(acc[r].x, acc[r].y);
      __half2 h1 = __floats2half2_rn(acc[r].z, acc[r].w);
      uint2 packed = make_uint2(*(unsigned int*)&h0, *(unsigned int*)&h1);
      *(uint2*)(Tp + (size_t)row * 16 + psl) = packed;
    }
  }
}

// Phase p (= blockIdx&3 -> XCDs {p,p+4} under bid%8 round-robin): gather 32 cols from the
// L2-resident panel. Wave = 4 edge sub-groups x 16 half2 slots; 32-edge batches.
__global__ __launch_bounds__(256) void k_agg(const unsigned int* __restrict__ T, const int* __restrict__ rowptr,
                                             const int2* __restrict__ edges, const float* __restrict__ dinv,
                                             const float* __restrict__ bias, float* __restrict__ hout,
                                             float* __restrict__ stats, int N) {
  int phase = blockIdx.x & 3;
  int chunk = blockIdx.x >> 2;
  int nchunks = gridDim.x >> 2;
  int tid = threadIdx.x;
  int wid = __builtin_amdgcn_readfirstlane(tid >> 6);
  int lane = tid & 63;
  int sub = lane >> 4;   // edge sub-group 0..3
  int slot = lane & 15;  // half2 slot (cols phase*32 + 2slot, +1)
  const unsigned int* __restrict__ Tp = T + (size_t)phase * N * 16;
  float bx = bias[phase * 32 + 2 * slot];
  float by = bias[phase * 32 + 2 * slot + 1];
  int gwave = chunk * 4 + wid;
  int nwaves = nchunks * 4;
  float sum0 = 0.f, sum1 = 0.f, sq0 = 0.f, sq1 = 0.f;
  for (int i = gwave; i < N; i += nwaves) {
    float di = dinv[i];
    float self = di * di;
    unsigned int u0 = Tp[(size_t)i * 16 + slot];
    float2 t0 = __half22float2(*(__half2*)&u0);
    float ax = (sub == 0) ? self * t0.x : 0.f;
    float ay = (sub == 0) ? self * t0.y : 0.f;
    int beg = rowptr[i], end = rowptr[i + 1];
    for (int e0 = beg; e0 < end; e0 += 32) {
      int ss[8];
      float vv[8];
#pragma unroll
      for (int k = 0; k < 8; ++k) {
        int eidx = e0 + 4 * k + sub;
        int2 ev = edges[eidx];  // padded alloc; masked below
        bool ok = eidx < end;
        ss[k] = ok ? ev.x : i;  // masked lanes re-gather hot row i
        vv[k] = ok ? __int_as_float(ev.y) : 0.f;
      }
      unsigned int uu[8];
#pragma unroll
      for (int k = 0; k < 8; ++k) uu[k] = Tp[(size_t)ss[k] * 16 + slot];
#pragma unroll
      for (int k = 0; k < 8; ++k) {
        float2 t = __half22float2(*(__half2*)&uu[k]);
        ax = fmaf(vv[k], t.x, ax);
        ay = fmaf(vv[k], t.y, ay);
      }
    }
    // reduce across the 4 edge sub-groups (lanes differing in bits 4,5)
    ax += __shfl_xor(ax, 16);
    ay += __shfl_xor(ay, 16);
    ax += __shfl_xor(ax, 32);
    ay += __shfl_xor(ay, 32);
    if (sub == 0) {
      ax += bx;
      ay += by;
      ((float2*)(hout + (size_t)i * DIM + phase * 32))[slot] = make_float2(ax, ay);
      sum0 += ax;
      sum1 += ay;
      sq0 = fmaf(ax, ax, sq0);
      sq1 = fmaf(ay, ay, sq1);
    }
  }
  __shared__ float red[4][16][4];
  if (sub == 0) {
    red[wid][slot][0] = sum0;
    red[wid][slot][1] = sum1;
    red[wid][slot][2] = sq0;
    red[wid][slot][3] = sq1;
  }
  __syncthreads();
  if (tid < 16) {
    int sl = tid;
    float a0 = red[0][sl][0] + red[1][sl][0] + red[2][sl][0] + red[3][sl][0];
    float a1 = red[0][sl][1] + red[1][sl][1] + red[2][sl][1] + red[3][sl][1];
    float q0 = red[0][sl][2] + red[1][sl][2] + red[2][sl][2] + red[3][sl][2];
    float q1 = red[0][sl][3] + red[1][sl][3] + red[2][sl][3] + red[3][sl][3];
    int c0 = phase * 32 + 2 * sl;
    atomicAdd(&stats[c0], a0);
    atomicAdd(&stats[c0 + 1], a1);
    atomicAdd(&stats[DIM + c0], q0);
    atomicAdd(&stats[DIM + c0 + 1], q1);
  }
}

__global__ __launch_bounds__(128) void k_bnstat(float* __restrict__ stats, const float* __restrict__ gamma,
                                                const float* __restrict__ beta, int N) {
  int c = threadIdx.x;
  float invN = 1.f / (float)N;
  float mu = stats[c] * invN;
  float var = stats[DIM + c] * invN - mu * mu;
  float rstd = rsqrtf(var + EPSV);
  float sc = gamma[c] * rstd;
  stats[2 * DIM + c] = sc;
  stats[3 * DIM + c] = beta[c] - mu * sc;
}

// pool mean of relu(sc*h+sh) per graph
__global__ __launch_bounds__(512) void k_pool(const float* __restrict__ h, const int* __restrict__ start,
                                              const float* __restrict__ invcnt, const float* __restrict__ scsh,
                                              float* __restrict__ pooled, int level) {
  int g = blockIdx.x;
  int s = start[g], e = start[g + 1];
  int c = threadIdx.x & 127;
  int stripe = threadIdx.x >> 7;  // 0..3
  float sc = scsh[c], sh = scsh[DIM + c];
  float acc = 0.f;
  for (int r = s + stripe; r < e; r += 4) acc += fmaxf(fmaf(h[(size_t)r * DIM + c], sc, sh), 0.f);
  __shared__ float red[4][DIM];
  red[stripe][c] = acc;
  __syncthreads();
  if (threadIdx.x < DIM) {
    float v = (red[0][c] + red[1][c] + red[2][c] + red[3][c]) * invcnt[g];
    pooled[(size_t)g * (3 * DIM) + level * DIM + c] = v;
  }
}

__global__ __launch_bounds__(512) void k_final(const float* __restrict__ pooled, const float* __restrict__ Wf,
                                               const float* __restrict__ bf, float* __restrict__ out) {
  int t = blockIdx.x * 512 + threadIdx.x;
  if (t >= NGRAPH * DIM) return;
  int j = t & (DIM - 1);
  int i = t >> 7;
  const float* prow = pooled + (size_t)i * (3 * DIM);
  float acc = bf[j];
  for (int k = 0; k < 3 * DIM; ++k) acc = fmaf(prow[k], Wf[(size_t)k * DIM + j], acc);
  out[t] = fmaxf(acc, 0.f);
}

// ---------------- launcher ----------------

extern "C" void kernel_launch(void* const* d_in, const int* in_sizes, int n_in,
                              void* d_out, int out_size, void* d_ws, size_t ws_size,
                              hipStream_t stream) {
  const float* x = (const float*)d_in[0];
  const int* ei = (const int*)d_in[1];
  const int* batch = (const int*)d_in[2];
  const float* W = (const float*)d_in[3];
  const float* b = (const float*)d_in[4];
  const float* gamma = (const float*)d_in[5];
  const float* beta = (const float*)d_in[6];
  const float* Wf = (const float*)d_in[7];
  const float* bf = (const float*)d_in[8];
  float* out = (float*)d_out;

  const int N = in_sizes[0] / DIM;   // 50000
  const int E = in_sizes[1] / 2;     // 800000

  char* base = (char*)d_ws;
  size_t off = 0;
  auto alloc = [&](size_t bytes) -> char* {
    char* p = base + off;
    off += (bytes + 255) & ~(size_t)255;
    return p;
  };
  float* h          = (float*)alloc((size_t)N * DIM * 4);
  unsigned int* T   = (unsigned int*)alloc((size_t)N * DIM * 2);  // 4 panels [N][16] u32
  int* cnt          = (int*)alloc((size_t)N * 4);
  int* cursor       = (int*)alloc((size_t)N * 4);
  int* rowptr       = (int*)alloc((size_t)(N + 1) * 4);
  int* partial      = (int*)alloc(256 * 4);
  float* dinv       = (float*)alloc((size_t)N * 4);
  int2* edges       = (int2*)alloc((size_t)(E + 32) * 8);  // +32 pad for overshoot batches
  float* stats      = (float*)alloc(4 * DIM * 4);  // colsum|colsumsq|scale|shift
  int* start        = (int*)alloc((NGRAPH + 1) * 4);
  float* invcnt     = (float*)alloc(NGRAPH * 4);
  float* pooled     = (float*)alloc((size_t)NGRAPH * 3 * DIM * 4);
  (void)ws_size;

  (void)hipMemsetAsync(cnt, 0, (size_t)N * 4, stream);
  (void)hipMemsetAsync(cursor, 0, (size_t)N * 4, stream);

  int nbScan = (N + 511) / 512;  // 98
  k_count<<<(E + 255) / 256, 256, 0, stream>>>(ei, cnt, E);
  k_blocksum<<<nbScan, 512, 0, stream>>>(cnt, partial, N);
  k_scanpartials<<<1, 128, 0, stream>>>(partial, nbScan);
  k_scan_write<<<nbScan, 512, 0, stream>>>(cnt, partial, rowptr, dinv, N);
  k_fill<<<(E + 255) / 256, 256, 0, stream>>>(ei, rowptr, cursor, dinv, edges, E);
  k_gstart<<<(N + 255) / 256, 256, 0, stream>>>(batch, start, N);
  k_invcnt<<<1, 512, 0, stream>>>(start, invcnt);

  int gemmGrid = (N + 31) / 32;
  for (int l = 0; l < 6; ++l) {
    const float* hin = (l == 0) ? x : h;
    const float* scsh = (l == 0) ? nullptr : stats + 2 * DIM;
    k_gemm<<<gemmGrid, 256, 0, stream>>>(hin, W + (size_t)l * DIM * DIM, scsh, T, stats, N);
    k_agg<<<2048, 256, 0, stream>>>(T, rowptr, edges, dinv, b + (size_t)l * DIM, h, stats, N);
    k_bnstat<<<1, 128, 0, stream>>>(stats, gamma + (size_t)l * DIM, beta + (size_t)l * DIM, N);
    if (l & 1) k_pool<<<NGRAPH, 512, 0, stream>>>(h, start, invcnt, stats + 2 * DIM, pooled, l >> 1);
  }
  k_final<<<(NGRAPH * DIM + 511) / 512, 512, 0, stream>>>(pooled, Wf, bf, out);
}

// Round 10
// 812.333 us; speedup vs baseline: 2.1518x; 1.0877x over previous
//
#include <hip/hip_runtime.h>
#include <hip/hip_fp16.h>

// HierarchicalEncoder: 6× (GCN -> BN -> ReLU) with level pooling + final linear.
// dst-CSR built once per call; per layer:
//   tmp16 = dinv * BNReLU(h) @ W[l]  (fp32 GEMM; dinv folded into fp16 panel output)
//   h     = dinv[i]*(sum tmp16[col] + tmp16[i]) + b   (edge = 4B col index ONLY;
//            phase-per-XCD-pair gather keeps each 3.2MB panel L2-resident)
// h stays PRE-BN fp32; consumers (next gemm, pool) apply scale/shift+relu on the fly.

#define DIM 128
#define NGRAPH 512
#define EPSV 1e-5f

// ---------------- preprocessing ----------------

__global__ __launch_bounds__(256) void k_count(const int* __restrict__ ei, int* __restrict__ cnt, int E) {
  int e = blockIdx.x * 256 + threadIdx.x;
  if (e < E) atomicAdd(&cnt[ei[E + e]], 1);
}

__global__ __launch_bounds__(512) void k_blocksum(const int* __restrict__ cnt, int* __restrict__ partial, int N) {
  __shared__ int sd[512];
  int idx = blockIdx.x * 512 + threadIdx.x;
  int v = (idx < N) ? cnt[idx] : 0;
  sd[threadIdx.x] = v;
  __syncthreads();
  for (int ofs = 256; ofs > 0; ofs >>= 1) {
    if (threadIdx.x < ofs) sd[threadIdx.x] += sd[threadIdx.x + ofs];
    __syncthreads();
  }
  if (threadIdx.x == 0) partial[blockIdx.x] = sd[0];
}

__global__ __launch_bounds__(128) void k_scanpartials(int* __restrict__ partial, int nb) {
  __shared__ int sp[128];
  int t = threadIdx.x;
  int v = (t < nb) ? partial[t] : 0;
  sp[t] = v;
  __syncthreads();
  for (int ofs = 1; ofs < 128; ofs <<= 1) {
    int a = (t >= ofs) ? sp[t - ofs] : 0;
    __syncthreads();
    sp[t] += a;
    __syncthreads();
  }
  if (t < nb) partial[t] = sp[t] - v;  // exclusive block offsets
}

__global__ __launch_bounds__(512) void k_scan_write(const int* __restrict__ cnt, const int* __restrict__ partial,
                                                    int* __restrict__ rowptr, float* __restrict__ dinv, int N) {
  __shared__ int sd[512];
  int tid = threadIdx.x;
  int idx = blockIdx.x * 512 + tid;
  int v = (idx < N) ? cnt[idx] : 0;
  sd[tid] = v;
  __syncthreads();
  for (int ofs = 1; ofs < 512; ofs <<= 1) {
    int a = (tid >= ofs) ? sd[tid - ofs] : 0;
    __syncthreads();
    sd[tid] += a;
    __syncthreads();
  }
  if (idx < N) {
    int excl = partial[blockIdx.x] + sd[tid] - v;
    rowptr[idx] = excl;
    dinv[idx] = rsqrtf((float)(v + 1));  // +1 for self loop
    if (idx == N - 1) rowptr[N] = excl + v;
  }
}

__global__ __launch_bounds__(256) void k_fill(const int* __restrict__ ei, const int* __restrict__ rowptr,
                                              int* __restrict__ cursor, int* __restrict__ cols, int E) {
  int e = blockIdx.x * 256 + threadIdx.x;
  if (e >= E) return;
  int s = ei[e];
  int d = ei[E + e];
  int pos = rowptr[d] + atomicAdd(&cursor[d], 1);
  cols[pos] = s;
}

__global__ __launch_bounds__(256) void k_gstart(const int* __restrict__ batch, int* __restrict__ start, int N) {
  int i = blockIdx.x * 256 + threadIdx.x;
  if (i >= N) return;
  int bi = batch[i];
  int prev = (i == 0) ? -1 : batch[i - 1];
  for (int g = prev + 1; g <= bi; ++g) start[g] = i;
  if (i == N - 1) {
    for (int g = bi + 1; g <= NGRAPH; ++g) start[g] = N;
  }
}

__global__ __launch_bounds__(512) void k_invcnt(const int* __restrict__ start, float* __restrict__ invcnt) {
  int g = threadIdx.x;
  if (g < NGRAPH) {
    int c = start[g + 1] - start[g];
    invcnt[g] = 1.0f / (float)max(c, 1);
  }
}

// ---------------- per-layer kernels ----------------

__device__ inline void fma4(float4& ar, float a, const float4& wv) {
  ar.x = fmaf(a, wv.x, ar.x);
  ar.y = fmaf(a, wv.y, ar.y);
  ar.z = fmaf(a, wv.z, ar.z);
  ar.w = fmaf(a, wv.w, ar.w);
}

// tmp16 = dinv[row] * act(A) @ W, stored fp16 in 4 column panels: panel p = cols 32p..32p+31,
// laid out [(N+1)][16] u32 (half2 slots); row N of each panel is ZERO (masked-gather target).
// act = relu(sc*a+sh) if scsh, else identity. W read straight from global (L1/L2-hot).
// Block 0 zeroes BN-stat accumulators and the 4 panel zero-rows.
__global__ __launch_bounds__(256) void k_gemm(const float* __restrict__ A, const float* __restrict__ Wl,
                                              const float* __restrict__ scsh,  // stats+256 | nullptr
                                              const float* __restrict__ dinv,
                                              unsigned int* __restrict__ T, float* __restrict__ stats, int N) {
  __shared__ float sH[32][DIM];
  int tid = threadIdx.x;
  size_t pstride = (size_t)(N + 1) * 16;
  if (blockIdx.x == 0) {
    stats[tid] = 0.f;  // colsum[128], colsumsq[128]
    if (tid < 64) {    // zero-row of each panel
      int p = tid >> 4, sl = tid & 15;
      T[(size_t)p * pstride + (size_t)N * 16 + sl] = 0u;
    }
  }
  int row0 = blockIdx.x * 32;
#pragma unroll
  for (int i = 0; i < 4; ++i) {
    int fi = tid + i * 256;  // 0..1023 float4 slots, 32 per row
    int r = fi >> 5, c4 = fi & 31;
    int row = row0 + r;
    float4 v = make_float4(0.f, 0.f, 0.f, 0.f);
    if (row < N) v = ((const float4*)(A + (size_t)row * DIM))[c4];
    if (scsh) {
      float4 sc = ((const float4*)scsh)[c4];
      float4 sh = ((const float4*)(scsh + DIM))[c4];
      v.x = fmaxf(fmaf(v.x, sc.x, sh.x), 0.f);
      v.y = fmaxf(fmaf(v.y, sc.y, sh.y), 0.f);
      v.z = fmaxf(fmaf(v.z, sc.z, sh.z), 0.f);
      v.w = fmaxf(fmaf(v.w, sc.w, sh.w), 0.f);
    }
    ((float4*)&sH[r][0])[c4] = v;
  }
  __syncthreads();
  int ct = tid & 31, rt = tid >> 5;  // 32 col-threads x 8 row-threads
  const float4* Wv = (const float4*)Wl;  // row k -> Wv[k*32 + ct]
  float4 acc[4];
#pragma unroll
  for (int r = 0; r < 4; ++r) acc[r] = make_float4(0.f, 0.f, 0.f, 0.f);
  for (int k4 = 0; k4 < 32; ++k4) {
    float4 wv0 = Wv[(4 * k4 + 0) * 32 + ct];
    float4 wv1 = Wv[(4 * k4 + 1) * 32 + ct];
    float4 wv2 = Wv[(4 * k4 + 2) * 32 + ct];
    float4 wv3 = Wv[(4 * k4 + 3) * 32 + ct];
#pragma unroll
    for (int r = 0; r < 4; ++r) {
      float4 av = *(const float4*)&sH[rt + 8 * r][4 * k4];
      fma4(acc[r], av.x, wv0);
      fma4(acc[r], av.y, wv1);
      fma4(acc[r], av.z, wv2);
      fma4(acc[r], av.w, wv3);
    }
  }
  int panel = ct >> 3;          // cols 4ct..4ct+3 live in panel ct/8
  int psl = (ct & 7) * 2;       // u32 slot within panel row
  unsigned int* Tp = T + (size_t)panel * pstride;
#pragma unroll
  for (int r = 0; r < 4; ++r) {
    int row = row0 + rt + 8 * r;
    if (row < N) {
      float dr = dinv[row];
      __half2 h0 = __floats2half2_rn(acc[r].x * dr, acc[r].y * dr);
      __half2 h1 = __floats2half2_rn(acc[r].z * dr, acc[r].w * dr);
      uint2 packed = make_uint2(*(unsigned int*)&h0, *(unsigned int*)&h1);
      *(uint2*)(Tp + (size_t)row * 16 + psl) = packed;
    }
  }
}

// Phase p (= blockIdx&3 -> XCDs {p,p+4} under bid%8 round-robin): gather 32 cols from the
// L2-resident panel. Wave = 4 edge sub-groups x 16 half2 slots; 32-edge batches.
// h[i] = dinv[i]*(sum_e tmp'[col_e] + tmp'[i]) + b; masked slots gather panel zero-row N.
__global__ __launch_bounds__(256) void k_agg(const unsigned int* __restrict__ T, const int* __restrict__ rowptr,
                                             const int* __restrict__ cols, const float* __restrict__ dinv,
                                             const float* __restrict__ bias, float* __restrict__ hout,
                                             float* __restrict__ stats, int N) {
  int phase = blockIdx.x & 3;
  int chunk = blockIdx.x >> 2;
  int nchunks = gridDim.x >> 2;
  int tid = threadIdx.x;
  int wid = __builtin_amdgcn_readfirstlane(tid >> 6);
  int lane = tid & 63;
  int sub = lane >> 4;   // edge sub-group 0..3
  int slot = lane & 15;  // half2 slot (cols phase*32 + 2slot, +1)
  const unsigned int* __restrict__ Tp = T + (size_t)phase * (N + 1) * 16;
  float bx = bias[phase * 32 + 2 * slot];
  float by = bias[phase * 32 + 2 * slot + 1];
  int gwave = chunk * 4 + wid;
  int nwaves = nchunks * 4;
  float sum0 = 0.f, sum1 = 0.f, sq0 = 0.f, sq1 = 0.f;
  for (int i = gwave; i < N; i += nwaves) {
    float ax = 0.f, ay = 0.f;
    if (sub == 0) {  // self term tmp'[i]
      unsigned int u0 = Tp[(size_t)i * 16 + slot];
      float2 t0 = __half22float2(*(__half2*)&u0);
      ax = t0.x;
      ay = t0.y;
    }
    int beg = rowptr[i], end = rowptr[i + 1];
    for (int e0 = beg; e0 < end; e0 += 32) {
      int ss[8];
#pragma unroll
      for (int k = 0; k < 8; ++k) {
        int eidx = e0 + 4 * k + sub;
        int cv = cols[eidx];        // padded alloc; masked below
        ss[k] = (eidx < end) ? cv : N;  // row N = zeros
      }
      unsigned int uu[8];
#pragma unroll
      for (int k = 0; k < 8; ++k) uu[k] = Tp[(size_t)ss[k] * 16 + slot];
#pragma unroll
      for (int k = 0; k < 8; ++k) {
        float2 t = __half22float2(*(__half2*)&uu[k]);
        ax += t.x;
        ay += t.y;
      }
    }
    // reduce across the 4 edge sub-groups (lanes differing in bits 4,5)
    ax += __shfl_xor(ax, 16);
    ay += __shfl_xor(ay, 16);
    ax += __shfl_xor(ax, 32);
    ay += __shfl_xor(ay, 32);
    if (sub == 0) {
      float di = dinv[i];
      ax = fmaf(di, ax, bx);
      ay = fmaf(di, ay, by);
      ((float2*)(hout + (size_t)i * DIM + phase * 32))[slot] = make_float2(ax, ay);
      sum0 += ax;
      sum1 += ay;
      sq0 = fmaf(ax, ax, sq0);
      sq1 = fmaf(ay, ay, sq1);
    }
  }
  __shared__ float red[4][16][4];
  if (sub == 0) {
    red[wid][slot][0] = sum0;
    red[wid][slot][1] = sum1;
    red[wid][slot][2] = sq0;
    red[wid][slot][3] = sq1;
  }
  __syncthreads();
  if (tid < 16) {
    int sl = tid;
    float a0 = red[0][sl][0] + red[1][sl][0] + red[2][sl][0] + red[3][sl][0];
    float a1 = red[0][sl][1] + red[1][sl][1] + red[2][sl][1] + red[3][sl][1];
    float q0 = red[0][sl][2] + red[1][sl][2] + red[2][sl][2] + red[3][sl][2];
    float q1 = red[0][sl][3] + red[1][sl][3] + red[2][sl][3] + red[3][sl][3];
    int c0 = phase * 32 + 2 * sl;
    atomicAdd(&stats[c0], a0);
    atomicAdd(&stats[c0 + 1], a1);
    atomicAdd(&stats[DIM + c0], q0);
    atomicAdd(&stats[DIM + c0 + 1], q1);
  }
}

__global__ __launch_bounds__(128) void k_bnstat(float* __restrict__ stats, const float* __restrict__ gamma,
                                                const float* __restrict__ beta, int N) {
  int c = threadIdx.x;
  float invN = 1.f / (float)N;
  float mu = stats[c] * invN;
  float var = stats[DIM + c] * invN - mu * mu;
  float rstd = rsqrtf(var + EPSV);
  float sc = gamma[c] * rstd;
  stats[2 * DIM + c] = sc;
  stats[3 * DIM + c] = beta[c] - mu * sc;
}

// pool mean of relu(sc*h+sh) per graph
__global__ __launch_bounds__(512) void k_pool(const float* __restrict__ h, const int* __restrict__ start,
                                              const float* __restrict__ invcnt, const float* __restrict__ scsh,
                                              float* __restrict__ pooled, int level) {
  int g = blockIdx.x;
  int s = start[g], e = start[g + 1];
  int c = threadIdx.x & 127;
  int stripe = threadIdx.x >> 7;  // 0..3
  float sc = scsh[c], sh = scsh[DIM + c];
  float acc = 0.f;
  for (int r = s + stripe; r < e; r += 4) acc += fmaxf(fmaf(h[(size_t)r * DIM + c], sc, sh), 0.f);
  __shared__ float red[4][DIM];
  red[stripe][c] = acc;
  __syncthreads();
  if (threadIdx.x < DIM) {
    float v = (red[0][c] + red[1][c] + red[2][c] + red[3][c]) * invcnt[g];
    pooled[(size_t)g * (3 * DIM) + level * DIM + c] = v;
  }
}

__global__ __launch_bounds__(512) void k_final(const float* __restrict__ pooled, const float* __restrict__ Wf,
                                               const float* __restrict__ bf, float* __restrict__ out) {
  int t = blockIdx.x * 512 + threadIdx.x;
  if (t >= NGRAPH * DIM) return;
  int j = t & (DIM - 1);
  int i = t >> 7;
  const float* prow = pooled + (size_t)i * (3 * DIM);
  float acc = bf[j];
  for (int k = 0; k < 3 * DIM; ++k) acc = fmaf(prow[k], Wf[(size_t)k * DIM + j], acc);
  out[t] = fmaxf(acc, 0.f);
}

// ---------------- launcher ----------------

extern "C" void kernel_launch(void* const* d_in, const int* in_sizes, int n_in,
                              void* d_out, int out_size, void* d_ws, size_t ws_size,
                              hipStream_t stream) {
  const float* x = (const float*)d_in[0];
  const int* ei = (const int*)d_in[1];
  const int* batch = (const int*)d_in[2];
  const float* W = (const float*)d_in[3];
  const float* b = (const float*)d_in[4];
  const float* gamma = (const float*)d_in[5];
  const float* beta = (const float*)d_in[6];
  const float* Wf = (const float*)d_in[7];
  const float* bf = (const float*)d_in[8];
  float* out = (float*)d_out;

  const int N = in_sizes[0] / DIM;   // 50000
  const int E = in_sizes[1] / 2;     // 800000

  char* base = (char*)d_ws;
  size_t off = 0;
  auto alloc = [&](size_t bytes) -> char* {
    char* p = base + off;
    off += (bytes + 255) & ~(size_t)255;
    return p;
  };
  float* h          = (float*)alloc((size_t)N * DIM * 4);
  unsigned int* T   = (unsigned int*)alloc((size_t)(N + 1) * DIM * 2);  // 4 panels [(N+1)][16] u32
  int* cnt          = (int*)alloc((size_t)N * 4);
  int* cursor       = (int*)alloc((size_t)N * 4);
  int* rowptr       = (int*)alloc((size_t)(N + 1) * 4);
  int* partial      = (int*)alloc(256 * 4);
  float* dinv       = (float*)alloc((size_t)N * 4);
  int* cols         = (int*)alloc((size_t)(E + 32) * 4);  // +32 pad for overshoot batches
  float* stats      = (float*)alloc(4 * DIM * 4);  // colsum|colsumsq|scale|shift
  int* start        = (int*)alloc((NGRAPH + 1) * 4);
  float* invcnt     = (float*)alloc(NGRAPH * 4);
  float* pooled     = (float*)alloc((size_t)NGRAPH * 3 * DIM * 4);
  (void)ws_size;

  (void)hipMemsetAsync(cnt, 0, (size_t)N * 4, stream);
  (void)hipMemsetAsync(cursor, 0, (size_t)N * 4, stream);

  int nbScan = (N + 511) / 512;  // 98
  k_count<<<(E + 255) / 256, 256, 0, stream>>>(ei, cnt, E);
  k_blocksum<<<nbScan, 512, 0, stream>>>(cnt, partial, N);
  k_scanpartials<<<1, 128, 0, stream>>>(partial, nbScan);
  k_scan_write<<<nbScan, 512, 0, stream>>>(cnt, partial, rowptr, dinv, N);
  k_fill<<<(E + 255) / 256, 256, 0, stream>>>(ei, rowptr, cursor, cols, E);
  k_gstart<<<(N + 255) / 256, 256, 0, stream>>>(batch, start, N);
  k_invcnt<<<1, 512, 0, stream>>>(start, invcnt);

  int gemmGrid = (N + 31) / 32;
  for (int l = 0; l < 6; ++l) {
    const float* hin = (l == 0) ? x : h;
    const float* scsh = (l == 0) ? nullptr : stats + 2 * DIM;
    k_gemm<<<gemmGrid, 256, 0, stream>>>(hin, W + (size_t)l * DIM * DIM, scsh, dinv, T, stats, N);
    k_agg<<<2048, 256, 0, stream>>>(T, rowptr, cols, dinv, b + (size_t)l * DIM, h, stats, N);
    k_bnstat<<<1, 128, 0, stream>>>(stats, gamma + (size_t)l * DIM, beta + (size_t)l * DIM, N);
    if (l & 1) k_pool<<<NGRAPH, 512, 0, stream>>>(h, start, invcnt, stats + 2 * DIM, pooled, l >> 1);
  }
  k_final<<<(NGRAPH * DIM + 511) / 512, 512, 0, stream>>>(pooled, Wf, bf, out);
}

// Round 11
// 779.387 us; speedup vs baseline: 2.2427x; 1.0423x over previous
//
#include <hip/hip_runtime.h>
#include <hip/hip_fp16.h>

// HierarchicalEncoder: 6× (GCN -> BN -> ReLU) with level pooling + final linear.
// dst-CSR built once per call; per layer:
//   tmp16 = dinv * BNReLU(h16) @ W[l]  (64-row-block fp32-acc GEMM; fp16 panel output)
//   h16   = dinv[i]*(sum tmp16[col] + tmp16[i]) + b   (uint16 col indices; fp16 h;
//            phase-per-XCD-pair gather keeps each 3.2MB panel L2-resident)
// h16 is PRE-BN fp16; consumers (next gemm, pool) apply scale/shift+relu in fp32.

#define DIM 128
#define NGRAPH 512
#define EPSV 1e-5f

// ---------------- preprocessing ----------------

__global__ __launch_bounds__(256) void k_count(const int* __restrict__ ei, int* __restrict__ cnt, int E) {
  int e = blockIdx.x * 256 + threadIdx.x;
  if (e < E) atomicAdd(&cnt[ei[E + e]], 1);
}

__global__ __launch_bounds__(512) void k_blocksum(const int* __restrict__ cnt, int* __restrict__ partial, int N) {
  __shared__ int sd[512];
  int idx = blockIdx.x * 512 + threadIdx.x;
  int v = (idx < N) ? cnt[idx] : 0;
  sd[threadIdx.x] = v;
  __syncthreads();
  for (int ofs = 256; ofs > 0; ofs >>= 1) {
    if (threadIdx.x < ofs) sd[threadIdx.x] += sd[threadIdx.x + ofs];
    __syncthreads();
  }
  if (threadIdx.x == 0) partial[blockIdx.x] = sd[0];
}

__global__ __launch_bounds__(128) void k_scanpartials(int* __restrict__ partial, int nb) {
  __shared__ int sp[128];
  int t = threadIdx.x;
  int v = (t < nb) ? partial[t] : 0;
  sp[t] = v;
  __syncthreads();
  for (int ofs = 1; ofs < 128; ofs <<= 1) {
    int a = (t >= ofs) ? sp[t - ofs] : 0;
    __syncthreads();
    sp[t] += a;
    __syncthreads();
  }
  if (t < nb) partial[t] = sp[t] - v;  // exclusive block offsets
}

__global__ __launch_bounds__(512) void k_scan_write(const int* __restrict__ cnt, const int* __restrict__ partial,
                                                    int* __restrict__ rowptr, float* __restrict__ dinv, int N) {
  __shared__ int sd[512];
  int tid = threadIdx.x;
  int idx = blockIdx.x * 512 + tid;
  int v = (idx < N) ? cnt[idx] : 0;
  sd[tid] = v;
  __syncthreads();
  for (int ofs = 1; ofs < 512; ofs <<= 1) {
    int a = (tid >= ofs) ? sd[tid - ofs] : 0;
    __syncthreads();
    sd[tid] += a;
    __syncthreads();
  }
  if (idx < N) {
    int excl = partial[blockIdx.x] + sd[tid] - v;
    rowptr[idx] = excl;
    dinv[idx] = rsqrtf((float)(v + 1));  // +1 for self loop
    if (idx == N - 1) rowptr[N] = excl + v;
  }
}

__global__ __launch_bounds__(256) void k_fill(const int* __restrict__ ei, const int* __restrict__ rowptr,
                                              int* __restrict__ cursor, unsigned short* __restrict__ cols, int E) {
  int e = blockIdx.x * 256 + threadIdx.x;
  if (e >= E) return;
  int s = ei[e];
  int d = ei[E + e];
  int pos = rowptr[d] + atomicAdd(&cursor[d], 1);
  cols[pos] = (unsigned short)s;
}

__global__ __launch_bounds__(256) void k_gstart(const int* __restrict__ batch, int* __restrict__ start, int N) {
  int i = blockIdx.x * 256 + threadIdx.x;
  if (i >= N) return;
  int bi = batch[i];
  int prev = (i == 0) ? -1 : batch[i - 1];
  for (int g = prev + 1; g <= bi; ++g) start[g] = i;
  if (i == N - 1) {
    for (int g = bi + 1; g <= NGRAPH; ++g) start[g] = N;
  }
}

__global__ __launch_bounds__(512) void k_invcnt(const int* __restrict__ start, float* __restrict__ invcnt) {
  int g = threadIdx.x;
  if (g < NGRAPH) {
    int c = start[g + 1] - start[g];
    invcnt[g] = 1.0f / (float)max(c, 1);
  }
}

// ---------------- per-layer kernels ----------------

__device__ inline void fma4(float4& ar, float a, const float4& wv) {
  ar.x = fmaf(a, wv.x, ar.x);
  ar.y = fmaf(a, wv.y, ar.y);
  ar.z = fmaf(a, wv.z, ar.z);
  ar.w = fmaf(a, wv.w, ar.w);
}

// tmp16 = dinv[row] * act(A) @ W; fp16 in 4 column panels [(N+1)][16] u32; row N = zeros.
// 64 rows per block. A is fp16 h (BN+ReLU applied in staging) or fp32 x at layer 0.
// Block 0 zeroes BN-stat accumulators and the 4 panel zero-rows.
__global__ __launch_bounds__(256) void k_gemm(const float* __restrict__ A32,          // layer 0 input | nullptr
                                              const unsigned int* __restrict__ A16,   // h16 | nullptr
                                              const float* __restrict__ Wl,
                                              const float* __restrict__ scsh,         // stats+256 | nullptr
                                              const float* __restrict__ dinv,
                                              unsigned int* __restrict__ T, float* __restrict__ stats, int N) {
  __shared__ float sH[64][DIM];
  int tid = threadIdx.x;
  size_t pstride = (size_t)(N + 1) * 16;
  if (blockIdx.x == 0) {
    stats[tid] = 0.f;  // colsum[128], colsumsq[128]
    if (tid < 64) {    // zero-row of each panel
      int p = tid >> 4, sl = tid & 15;
      T[(size_t)p * pstride + (size_t)N * 16 + sl] = 0u;
    }
  }
  int row0 = blockIdx.x * 64;
#pragma unroll
  for (int i = 0; i < 8; ++i) {
    int fi = tid + i * 256;  // 0..2047 float4 slots, 32 per row
    int r = fi >> 5, c4 = fi & 31;
    int row = row0 + r;
    float4 v = make_float4(0.f, 0.f, 0.f, 0.f);
    if (scsh) {
      if (row < N) {
        uint2 u = ((const uint2*)(A16 + (size_t)row * 64))[c4];
        float2 lo = __half22float2(*(__half2*)&u.x);
        float2 hi = __half22float2(*(__half2*)&u.y);
        float4 sc = ((const float4*)scsh)[c4];
        float4 sh = ((const float4*)(scsh + DIM))[c4];
        v.x = fmaxf(fmaf(lo.x, sc.x, sh.x), 0.f);
        v.y = fmaxf(fmaf(lo.y, sc.y, sh.y), 0.f);
        v.z = fmaxf(fmaf(hi.x, sc.z, sh.z), 0.f);
        v.w = fmaxf(fmaf(hi.y, sc.w, sh.w), 0.f);
      }
    } else {
      if (row < N) v = ((const float4*)(A32 + (size_t)row * DIM))[c4];
    }
    ((float4*)&sH[r][0])[c4] = v;
  }
  __syncthreads();
  int ct = tid & 31, rt = tid >> 5;  // 32 col-threads x 8 row-threads; rows rt+8r
  const float4* Wv = (const float4*)Wl;  // row k -> Wv[k*32 + ct]
  float4 acc[8];
#pragma unroll
  for (int r = 0; r < 8; ++r) acc[r] = make_float4(0.f, 0.f, 0.f, 0.f);
  for (int k4 = 0; k4 < 32; ++k4) {
    float4 wv0 = Wv[(4 * k4 + 0) * 32 + ct];
    float4 wv1 = Wv[(4 * k4 + 1) * 32 + ct];
    float4 wv2 = Wv[(4 * k4 + 2) * 32 + ct];
    float4 wv3 = Wv[(4 * k4 + 3) * 32 + ct];
#pragma unroll
    for (int r = 0; r < 8; ++r) {
      float4 av = *(const float4*)&sH[rt + 8 * r][4 * k4];
      fma4(acc[r], av.x, wv0);
      fma4(acc[r], av.y, wv1);
      fma4(acc[r], av.z, wv2);
      fma4(acc[r], av.w, wv3);
    }
  }
  int panel = ct >> 3;          // cols 4ct..4ct+3 live in panel ct/8
  int psl = (ct & 7) * 2;       // u32 slot within panel row
  unsigned int* Tp = T + (size_t)panel * pstride;
#pragma unroll
  for (int r = 0; r < 8; ++r) {
    int row = row0 + rt + 8 * r;
    if (row < N) {
      float dr = dinv[row];
      __half2 h0 = __floats2half2_rn(acc[r].x * dr, acc[r].y * dr);
      __half2 h1 = __floats2half2_rn(acc[r].z * dr, acc[r].w * dr);
      uint2 packed = make_uint2(*(unsigned int*)&h0, *(unsigned int*)&h1);
      *(uint2*)(Tp + (size_t)row * 16 + psl) = packed;
    }
  }
}

// Phase p (= blockIdx&3 -> XCDs {p,p+4} under bid%8 round-robin): gather 32 cols from the
// L2-resident panel. Wave = 4 edge sub-groups x 16 half2 slots; 32-edge batches.
// h16[i] = dinv[i]*(sum_e tmp'[col_e] + tmp'[i]) + b (packed half2); BN stats from fp32.
__global__ __launch_bounds__(256) void k_agg(const unsigned int* __restrict__ T, const int* __restrict__ rowptr,
                                             const unsigned short* __restrict__ cols, const float* __restrict__ dinv,
                                             const float* __restrict__ bias, unsigned int* __restrict__ hout,
                                             float* __restrict__ stats, int N) {
  int phase = blockIdx.x & 3;
  int chunk = blockIdx.x >> 2;
  int nchunks = gridDim.x >> 2;
  int tid = threadIdx.x;
  int wid = __builtin_amdgcn_readfirstlane(tid >> 6);
  int lane = tid & 63;
  int sub = lane >> 4;   // edge sub-group 0..3
  int slot = lane & 15;  // half2 slot (cols phase*32 + 2slot, +1)
  const unsigned int* __restrict__ Tp = T + (size_t)phase * (N + 1) * 16;
  float bx = bias[phase * 32 + 2 * slot];
  float by = bias[phase * 32 + 2 * slot + 1];
  int gwave = chunk * 4 + wid;
  int nwaves = nchunks * 4;
  float sum0 = 0.f, sum1 = 0.f, sq0 = 0.f, sq1 = 0.f;
  for (int i = gwave; i < N; i += nwaves) {
    float ax = 0.f, ay = 0.f;
    if (sub == 0) {  // self term tmp'[i]
      unsigned int u0 = Tp[(size_t)i * 16 + slot];
      float2 t0 = __half22float2(*(__half2*)&u0);
      ax = t0.x;
      ay = t0.y;
    }
    int beg = rowptr[i], end = rowptr[i + 1];
    for (int e0 = beg; e0 < end; e0 += 32) {
      int ss[8];
#pragma unroll
      for (int k = 0; k < 8; ++k) {
        int eidx = e0 + 4 * k + sub;
        int cv = (int)cols[eidx];       // padded alloc; masked below
        ss[k] = (eidx < end) ? cv : N;  // row N = zeros
      }
      unsigned int uu[8];
#pragma unroll
      for (int k = 0; k < 8; ++k) uu[k] = Tp[(size_t)ss[k] * 16 + slot];
#pragma unroll
      for (int k = 0; k < 8; ++k) {
        float2 t = __half22float2(*(__half2*)&uu[k]);
        ax += t.x;
        ay += t.y;
      }
    }
    // reduce across the 4 edge sub-groups (lanes differing in bits 4,5)
    ax += __shfl_xor(ax, 16);
    ay += __shfl_xor(ay, 16);
    ax += __shfl_xor(ax, 32);
    ay += __shfl_xor(ay, 32);
    if (sub == 0) {
      float di = dinv[i];
      ax = fmaf(di, ax, bx);
      ay = fmaf(di, ay, by);
      __half2 hp = __floats2half2_rn(ax, ay);
      hout[(size_t)i * 64 + phase * 16 + slot] = *(unsigned int*)&hp;
      sum0 += ax;
      sum1 += ay;
      sq0 = fmaf(ax, ax, sq0);
      sq1 = fmaf(ay, ay, sq1);
    }
  }
  __shared__ float red[4][16][4];
  if (sub == 0) {
    red[wid][slot][0] = sum0;
    red[wid][slot][1] = sum1;
    red[wid][slot][2] = sq0;
    red[wid][slot][3] = sq1;
  }
  __syncthreads();
  if (tid < 16) {
    int sl = tid;
    float a0 = red[0][sl][0] + red[1][sl][0] + red[2][sl][0] + red[3][sl][0];
    float a1 = red[0][sl][1] + red[1][sl][1] + red[2][sl][1] + red[3][sl][1];
    float q0 = red[0][sl][2] + red[1][sl][2] + red[2][sl][2] + red[3][sl][2];
    float q1 = red[0][sl][3] + red[1][sl][3] + red[2][sl][3] + red[3][sl][3];
    int c0 = phase * 32 + 2 * sl;
    atomicAdd(&stats[c0], a0);
    atomicAdd(&stats[c0 + 1], a1);
    atomicAdd(&stats[DIM + c0], q0);
    atomicAdd(&stats[DIM + c0 + 1], q1);
  }
}

__global__ __launch_bounds__(128) void k_bnstat(float* __restrict__ stats, const float* __restrict__ gamma,
                                                const float* __restrict__ beta, int N) {
  int c = threadIdx.x;
  float invN = 1.f / (float)N;
  float mu = stats[c] * invN;
  float var = stats[DIM + c] * invN - mu * mu;
  float rstd = rsqrtf(var + EPSV);
  float sc = gamma[c] * rstd;
  stats[2 * DIM + c] = sc;
  stats[3 * DIM + c] = beta[c] - mu * sc;
}

// pool mean of relu(sc*h+sh) per graph; h is fp16 (u32 half2 slots)
__global__ __launch_bounds__(512) void k_pool(const unsigned int* __restrict__ h16, const int* __restrict__ start,
                                              const float* __restrict__ invcnt, const float* __restrict__ scsh,
                                              float* __restrict__ pooled, int level) {
  int g = blockIdx.x;
  int s = start[g], e = start[g + 1];
  int slot = threadIdx.x & 63;   // u32 slot = cols 2slot, 2slot+1
  int stripe = threadIdx.x >> 6; // 0..7
  float scx = scsh[2 * slot], scy = scsh[2 * slot + 1];
  float shx = scsh[DIM + 2 * slot], shy = scsh[DIM + 2 * slot + 1];
  float ax = 0.f, ay = 0.f;
  for (int r = s + stripe; r < e; r += 8) {
    unsigned int u = h16[(size_t)r * 64 + slot];
    float2 t = __half22float2(*(__half2*)&u);
    ax += fmaxf(fmaf(t.x, scx, shx), 0.f);
    ay += fmaxf(fmaf(t.y, scy, shy), 0.f);
  }
  __shared__ float red[8][64][2];
  red[stripe][slot][0] = ax;
  red[stripe][slot][1] = ay;
  __syncthreads();
  if (threadIdx.x < 64) {
    int sl = threadIdx.x;
    float vx = 0.f, vy = 0.f;
#pragma unroll
    for (int st = 0; st < 8; ++st) {
      vx += red[st][sl][0];
      vy += red[st][sl][1];
    }
    float ic = invcnt[g];
    float* dst = pooled + (size_t)g * (3 * DIM) + level * DIM + 2 * sl;
    dst[0] = vx * ic;
    dst[1] = vy * ic;
  }
}

__global__ __launch_bounds__(512) void k_final(const float* __restrict__ pooled, const float* __restrict__ Wf,
                                               const float* __restrict__ bf, float* __restrict__ out) {
  int t = blockIdx.x * 512 + threadIdx.x;
  if (t >= NGRAPH * DIM) return;
  int j = t & (DIM - 1);
  int i = t >> 7;
  const float* prow = pooled + (size_t)i * (3 * DIM);
  float acc = bf[j];
  for (int k = 0; k < 3 * DIM; ++k) acc = fmaf(prow[k], Wf[(size_t)k * DIM + j], acc);
  out[t] = fmaxf(acc, 0.f);
}

// ---------------- launcher ----------------

extern "C" void kernel_launch(void* const* d_in, const int* in_sizes, int n_in,
                              void* d_out, int out_size, void* d_ws, size_t ws_size,
                              hipStream_t stream) {
  const float* x = (const float*)d_in[0];
  const int* ei = (const int*)d_in[1];
  const int* batch = (const int*)d_in[2];
  const float* W = (const float*)d_in[3];
  const float* b = (const float*)d_in[4];
  const float* gamma = (const float*)d_in[5];
  const float* beta = (const float*)d_in[6];
  const float* Wf = (const float*)d_in[7];
  const float* bf = (const float*)d_in[8];
  float* out = (float*)d_out;

  const int N = in_sizes[0] / DIM;   // 50000
  const int E = in_sizes[1] / 2;     // 800000

  char* base = (char*)d_ws;
  size_t off = 0;
  auto alloc = [&](size_t bytes) -> char* {
    char* p = base + off;
    off += (bytes + 255) & ~(size_t)255;
    return p;
  };
  unsigned int* h16 = (unsigned int*)alloc((size_t)N * DIM * 2);           // fp16 h, 64 u32/row
  unsigned int* T   = (unsigned int*)alloc((size_t)(N + 1) * DIM * 2);     // 4 panels [(N+1)][16] u32
  int* cnt          = (int*)alloc((size_t)N * 4);
  int* cursor       = (int*)alloc((size_t)N * 4);
  int* rowptr       = (int*)alloc((size_t)(N + 1) * 4);
  int* partial      = (int*)alloc(256 * 4);
  float* dinv       = (float*)alloc((size_t)N * 4);
  unsigned short* cols = (unsigned short*)alloc((size_t)(E + 32) * 2);     // +32 pad for overshoot
  float* stats      = (float*)alloc(4 * DIM * 4);  // colsum|colsumsq|scale|shift
  int* start        = (int*)alloc((NGRAPH + 1) * 4);
  float* invcnt     = (float*)alloc(NGRAPH * 4);
  float* pooled     = (float*)alloc((size_t)NGRAPH * 3 * DIM * 4);
  (void)ws_size;

  (void)hipMemsetAsync(cnt, 0, (size_t)N * 4, stream);
  (void)hipMemsetAsync(cursor, 0, (size_t)N * 4, stream);

  int nbScan = (N + 511) / 512;  // 98
  k_count<<<(E + 255) / 256, 256, 0, stream>>>(ei, cnt, E);
  k_blocksum<<<nbScan, 512, 0, stream>>>(cnt, partial, N);
  k_scanpartials<<<1, 128, 0, stream>>>(partial, nbScan);
  k_scan_write<<<nbScan, 512, 0, stream>>>(cnt, partial, rowptr, dinv, N);
  k_fill<<<(E + 255) / 256, 256, 0, stream>>>(ei, rowptr, cursor, cols, E);
  k_gstart<<<(N + 255) / 256, 256, 0, stream>>>(batch, start, N);
  k_invcnt<<<1, 512, 0, stream>>>(start, invcnt);

  int gemmGrid = (N + 63) / 64;
  for (int l = 0; l < 6; ++l) {
    const float* scsh = (l == 0) ? nullptr : stats + 2 * DIM;
    k_gemm<<<gemmGrid, 256, 0, stream>>>((l == 0) ? x : nullptr, (l == 0) ? nullptr : h16,
                                         W + (size_t)l * DIM * DIM, scsh, dinv, T, stats, N);
    k_agg<<<2048, 256, 0, stream>>>(T, rowptr, cols, dinv, b + (size_t)l * DIM, h16, stats, N);
    k_bnstat<<<1, 128, 0, stream>>>(stats, gamma + (size_t)l * DIM, beta + (size_t)l * DIM, N);
    if (l & 1) k_pool<<<NGRAPH, 512, 0, stream>>>(h16, start, invcnt, stats + 2 * DIM, pooled, l >> 1);
  }
  k_final<<<(NGRAPH * DIM + 511) / 512, 512, 0, stream>>>(pooled, Wf, bf, out);
}

// Round 12
// 693.615 us; speedup vs baseline: 2.5200x; 1.1237x over previous
//
#include <hip/hip_runtime.h>
#include <hip/hip_fp16.h>

// HierarchicalEncoder: 6× (GCN -> BN -> ReLU) with level pooling + final linear.
// Per layer:
//   tmp16 = dinv * BNReLU(h16) @ W16   (MFMA 16x16x32 f16 GEMM, W^T fp16 in LDS,
//                                       BN of prev layer computed inline + fused in staging)
//   h16   = dinv[i]*(sum tmp16[col] + tmp16[i]) + b   (u16 cols; 4-phase XCD-local panels)
// Per-layer BN stat buffers; no separate bnstat kernel.

#define DIM 128
#define NGRAPH 512
#define EPSV 1e-5f

typedef _Float16 f16x8 __attribute__((ext_vector_type(8)));
typedef float f32x4 __attribute__((ext_vector_type(4)));

// ---------------- preprocessing ----------------

__global__ __launch_bounds__(256) void k_count(const int* __restrict__ ei, int* __restrict__ cnt, int E) {
  int e = blockIdx.x * 256 + threadIdx.x;
  if (e < E) atomicAdd(&cnt[ei[E + e]], 1);
}

__global__ __launch_bounds__(512) void k_blocksum(const int* __restrict__ cnt, int* __restrict__ partial, int N) {
  __shared__ int sd[512];
  int idx = blockIdx.x * 512 + threadIdx.x;
  int v = (idx < N) ? cnt[idx] : 0;
  sd[threadIdx.x] = v;
  __syncthreads();
  for (int ofs = 256; ofs > 0; ofs >>= 1) {
    if (threadIdx.x < ofs) sd[threadIdx.x] += sd[threadIdx.x + ofs];
    __syncthreads();
  }
  if (threadIdx.x == 0) partial[blockIdx.x] = sd[0];
}

__global__ __launch_bounds__(128) void k_scanpartials(int* __restrict__ partial, int nb) {
  __shared__ int sp[128];
  int t = threadIdx.x;
  int v = (t < nb) ? partial[t] : 0;
  sp[t] = v;
  __syncthreads();
  for (int ofs = 1; ofs < 128; ofs <<= 1) {
    int a = (t >= ofs) ? sp[t - ofs] : 0;
    __syncthreads();
    sp[t] += a;
    __syncthreads();
  }
  if (t < nb) partial[t] = sp[t] - v;  // exclusive block offsets
}

__global__ __launch_bounds__(512) void k_scan_write(const int* __restrict__ cnt, const int* __restrict__ partial,
                                                    int* __restrict__ rowptr, float* __restrict__ dinv, int N) {
  __shared__ int sd[512];
  int tid = threadIdx.x;
  int idx = blockIdx.x * 512 + tid;
  int v = (idx < N) ? cnt[idx] : 0;
  sd[tid] = v;
  __syncthreads();
  for (int ofs = 1; ofs < 512; ofs <<= 1) {
    int a = (tid >= ofs) ? sd[tid - ofs] : 0;
    __syncthreads();
    sd[tid] += a;
    __syncthreads();
  }
  if (idx < N) {
    int excl = partial[blockIdx.x] + sd[tid] - v;
    rowptr[idx] = excl;
    dinv[idx] = rsqrtf((float)(v + 1));  // +1 for self loop
    if (idx == N - 1) rowptr[N] = excl + v;
  }
}

__global__ __launch_bounds__(256) void k_fill(const int* __restrict__ ei, const int* __restrict__ rowptr,
                                              int* __restrict__ cursor, unsigned short* __restrict__ cols, int E) {
  int e = blockIdx.x * 256 + threadIdx.x;
  if (e >= E) return;
  int s = ei[e];
  int d = ei[E + e];
  int pos = rowptr[d] + atomicAdd(&cursor[d], 1);
  cols[pos] = (unsigned short)s;
}

__global__ __launch_bounds__(256) void k_gstart(const int* __restrict__ batch, int* __restrict__ start, int N) {
  int i = blockIdx.x * 256 + threadIdx.x;
  if (i >= N) return;
  int bi = batch[i];
  int prev = (i == 0) ? -1 : batch[i - 1];
  for (int g = prev + 1; g <= bi; ++g) start[g] = i;
  if (i == N - 1) {
    for (int g = bi + 1; g <= NGRAPH; ++g) start[g] = N;
  }
}

__global__ __launch_bounds__(512) void k_invcnt(const int* __restrict__ start, float* __restrict__ invcnt) {
  int g = threadIdx.x;
  if (g < NGRAPH) {
    int c = start[g + 1] - start[g];
    invcnt[g] = 1.0f / (float)max(c, 1);
  }
}

// W16T[l][n][k] = fp16(W[l][k][n]) — B-operand layout for MFMA (contiguous k per col)
__global__ __launch_bounds__(256) void k_prepw(const float* __restrict__ W, _Float16* __restrict__ W16T) {
  int idx = blockIdx.x * 256 + threadIdx.x;
  if (idx >= 6 * 16384) return;
  int l = idx >> 14, rem = idx & 16383;
  int k = rem >> 7, n = rem & 127;
  W16T[(size_t)l * 16384 + (size_t)n * 128 + k] = (_Float16)W[(size_t)l * 16384 + (size_t)k * 128 + n];
}

// ---------------- per-layer kernels ----------------

#define PITCH 136  // padded halves per LDS row (bank-conflict break)

// tmp16 = dinv[row] * act(A) @ W  via MFMA f16; fp16 panels [(N+1)][16] u32; row N = zeros.
// 64 rows/block, 4 waves; wave w = rows 16w..16w+15, all 128 cols.
// act = relu(sc*a+sh) with sc/sh computed inline from prev-layer raw stats, or identity (l=0).
__global__ __launch_bounds__(256) void k_gemm(const float* __restrict__ A32,         // layer-0 x | nullptr
                                              const unsigned int* __restrict__ A16,  // h16 | nullptr
                                              const _Float16* __restrict__ W16T,     // [128 n][128 k]
                                              const float* __restrict__ statsPrev,   // raw sums | nullptr
                                              const float* __restrict__ gammaP, const float* __restrict__ betaP,
                                              const float* __restrict__ dinv,
                                              unsigned int* __restrict__ T, int N) {
  __shared__ _Float16 sW[128 * PITCH];
  __shared__ _Float16 sA[64 * PITCH];
  __shared__ float sScSh[256];
  int tid = threadIdx.x;
  size_t pstride = (size_t)(N + 1) * 16;
  if (blockIdx.x == 0 && tid < 64) {  // zero-row of each panel (masked-gather target)
    int p = tid >> 4, sl = tid & 15;
    T[(size_t)p * pstride + (size_t)N * 16 + sl] = 0u;
  }
  if (statsPrev && tid < 128) {  // inline BN scale/shift from raw sums
    float invN = 1.f / (float)N;
    float mu = statsPrev[tid] * invN;
    float var = statsPrev[128 + tid] * invN - mu * mu;
    float sc = gammaP[tid] * rsqrtf(var + EPSV);
    sScSh[tid] = sc;
    sScSh[128 + tid] = betaP[tid] - mu * sc;
  }
  // stage W^T into LDS (padded rows)
#pragma unroll
  for (int i = 0; i < 16; ++i) {
    int f = (tid + i * 256) * 4;  // f16 index, 4 per thread-step
    int n = f >> 7, k = f & 127;
    *(uint2*)&sW[n * PITCH + k] = *(const uint2*)&W16T[n * 128 + k];
  }
  __syncthreads();  // sScSh ready for sA staging
  int row0 = blockIdx.x * 64;
#pragma unroll
  for (int i = 0; i < 8; ++i) {
    int f = (tid + i * 256) * 4;
    int r = f >> 7, c = f & 127;
    int row = row0 + r;
    uint2 outp = make_uint2(0u, 0u);
    if (row < N) {
      float v0, v1, v2, v3;
      if (statsPrev) {
        uint2 u = *(const uint2*)&A16[(size_t)row * 64 + (c >> 1)];
        float2 lo = __half22float2(*(__half2*)&u.x);
        float2 hi = __half22float2(*(__half2*)&u.y);
        v0 = fmaxf(fmaf(lo.x, sScSh[c], sScSh[128 + c]), 0.f);
        v1 = fmaxf(fmaf(lo.y, sScSh[c + 1], sScSh[128 + c + 1]), 0.f);
        v2 = fmaxf(fmaf(hi.x, sScSh[c + 2], sScSh[128 + c + 2]), 0.f);
        v3 = fmaxf(fmaf(hi.y, sScSh[c + 3], sScSh[128 + c + 3]), 0.f);
      } else {
        float4 v = *(const float4*)&A32[(size_t)row * 128 + c];
        v0 = v.x; v1 = v.y; v2 = v.z; v3 = v.w;
      }
      __half2 h0 = __floats2half2_rn(v0, v1);
      __half2 h1 = __floats2half2_rn(v2, v3);
      outp = make_uint2(*(unsigned int*)&h0, *(unsigned int*)&h1);
    }
    *(uint2*)&sA[r * PITCH + c] = outp;
  }
  __syncthreads();
  // MFMA: wave w -> rows 16w..16w+15; 8 col-tiles x 4 K-steps
  int w = tid >> 6;
  int l = tid & 63;
  int m = l & 15, kg = l >> 4;
  int rowbase = 16 * w;
  f16x8 af[4];
#pragma unroll
  for (int ks = 0; ks < 4; ++ks)
    af[ks] = *(const f16x8*)&sA[(rowbase + m) * PITCH + ks * 32 + kg * 8];
  f32x4 acc[8] = {};
#pragma unroll
  for (int t8 = 0; t8 < 8; ++t8) {
#pragma unroll
    for (int ks = 0; ks < 4; ++ks) {
      f16x8 bf = *(const f16x8*)&sW[(t8 * 16 + m) * PITCH + ks * 32 + kg * 8];
      acc[t8] = __builtin_amdgcn_mfma_f32_16x16x32_f16(af[ks], bf, acc[t8], 0, 0, 0);
    }
  }
  // epilogue: D col = 16*t8 + (lane&15), row = rowbase + (lane>>4)*4 + j (verified mapping)
  float dv[4];
#pragma unroll
  for (int j = 0; j < 4; ++j) {
    int row = row0 + rowbase + kg * 4 + j;
    dv[j] = (row < N) ? dinv[row] : 0.f;
  }
#pragma unroll
  for (int t8 = 0; t8 < 8; ++t8) {
#pragma unroll
    for (int j = 0; j < 4; ++j)
      sA[(rowbase + kg * 4 + j) * PITCH + t8 * 16 + m] = (_Float16)(acc[t8][j] * dv[j]);
  }
  __syncthreads();
  // cooperative packed store into the 4 column panels
#pragma unroll
  for (int i = 0; i < 8; ++i) {
    int idx = tid + i * 256;
    int r = idx >> 5, q = idx & 31;  // q = uint2 group (4 cols)
    int row = row0 + r;
    if (row < N) {
      uint2 val = *(const uint2*)((const char*)sA + r * (PITCH * 2) + q * 8);
      int p = q >> 3, psl = (q & 7) * 2;
      *(uint2*)&T[(size_t)p * pstride + (size_t)row * 16 + psl] = val;
    }
  }
}

// Phase p (= blockIdx&3): gather 32 cols from the L2-resident panel.
// Wave = 4 edge sub-groups x 16 half2 slots; 32-edge batches; masked slots hit zero-row N.
__global__ __launch_bounds__(256) void k_agg(const unsigned int* __restrict__ T, const int* __restrict__ rowptr,
                                             const unsigned short* __restrict__ cols, const float* __restrict__ dinv,
                                             const float* __restrict__ bias, unsigned int* __restrict__ hout,
                                             float* __restrict__ stats, int N) {
  int phase = blockIdx.x & 3;
  int chunk = blockIdx.x >> 2;
  int nchunks = gridDim.x >> 2;
  int tid = threadIdx.x;
  int wid = __builtin_amdgcn_readfirstlane(tid >> 6);
  int lane = tid & 63;
  int sub = lane >> 4;   // edge sub-group 0..3
  int slot = lane & 15;  // half2 slot (cols phase*32 + 2slot, +1)
  const unsigned int* __restrict__ Tp = T + (size_t)phase * (N + 1) * 16;
  float bx = bias[phase * 32 + 2 * slot];
  float by = bias[phase * 32 + 2 * slot + 1];
  int gwave = chunk * 4 + wid;
  int nwaves = nchunks * 4;
  float sum0 = 0.f, sum1 = 0.f, sq0 = 0.f, sq1 = 0.f;
  for (int i = gwave; i < N; i += nwaves) {
    float ax = 0.f, ay = 0.f;
    if (sub == 0) {  // self term tmp'[i]
      unsigned int u0 = Tp[(size_t)i * 16 + slot];
      float2 t0 = __half22float2(*(__half2*)&u0);
      ax = t0.x;
      ay = t0.y;
    }
    int beg = rowptr[i], end = rowptr[i + 1];
    for (int e0 = beg; e0 < end; e0 += 32) {
      int ss[8];
#pragma unroll
      for (int k = 0; k < 8; ++k) {
        int eidx = e0 + 4 * k + sub;
        int cv = (int)cols[eidx];       // padded alloc; masked below
        ss[k] = (eidx < end) ? cv : N;  // row N = zeros
      }
      unsigned int uu[8];
#pragma unroll
      for (int k = 0; k < 8; ++k) uu[k] = Tp[(size_t)ss[k] * 16 + slot];
#pragma unroll
      for (int k = 0; k < 8; ++k) {
        float2 t = __half22float2(*(__half2*)&uu[k]);
        ax += t.x;
        ay += t.y;
      }
    }
    ax += __shfl_xor(ax, 16);
    ay += __shfl_xor(ay, 16);
    ax += __shfl_xor(ax, 32);
    ay += __shfl_xor(ay, 32);
    if (sub == 0) {
      float di = dinv[i];
      ax = fmaf(di, ax, bx);
      ay = fmaf(di, ay, by);
      __half2 hp = __floats2half2_rn(ax, ay);
      hout[(size_t)i * 64 + phase * 16 + slot] = *(unsigned int*)&hp;
      sum0 += ax;
      sum1 += ay;
      sq0 = fmaf(ax, ax, sq0);
      sq1 = fmaf(ay, ay, sq1);
    }
  }
  __shared__ float red[4][16][4];
  if (sub == 0) {
    red[wid][slot][0] = sum0;
    red[wid][slot][1] = sum1;
    red[wid][slot][2] = sq0;
    red[wid][slot][3] = sq1;
  }
  __syncthreads();
  if (tid < 16) {
    int sl = tid;
    float a0 = red[0][sl][0] + red[1][sl][0] + red[2][sl][0] + red[3][sl][0];
    float a1 = red[0][sl][1] + red[1][sl][1] + red[2][sl][1] + red[3][sl][1];
    float q0 = red[0][sl][2] + red[1][sl][2] + red[2][sl][2] + red[3][sl][2];
    float q1 = red[0][sl][3] + red[1][sl][3] + red[2][sl][3] + red[3][sl][3];
    int c0 = phase * 32 + 2 * sl;
    atomicAdd(&stats[c0], a0);
    atomicAdd(&stats[c0 + 1], a1);
    atomicAdd(&stats[DIM + c0], q0);
    atomicAdd(&stats[DIM + c0 + 1], q1);
  }
}

// pool mean of relu(sc*h+sh) per graph; sc/sh computed inline from raw stats
__global__ __launch_bounds__(512) void k_pool(const unsigned int* __restrict__ h16, const int* __restrict__ start,
                                              const float* __restrict__ invcnt, const float* __restrict__ statsL,
                                              const float* __restrict__ gammaL, const float* __restrict__ betaL,
                                              float* __restrict__ pooled, int level, int N) {
  int g = blockIdx.x;
  int s = start[g], e = start[g + 1];
  int slot = threadIdx.x & 63;   // u32 slot = cols 2slot, 2slot+1
  int stripe = threadIdx.x >> 6; // 0..7
  float invN = 1.f / (float)N;
  int c0 = 2 * slot, c1 = c0 + 1;
  float mu0 = statsL[c0] * invN, mu1 = statsL[c1] * invN;
  float var0 = statsL[DIM + c0] * invN - mu0 * mu0;
  float var1 = statsL[DIM + c1] * invN - mu1 * mu1;
  float scx = gammaL[c0] * rsqrtf(var0 + EPSV);
  float scy = gammaL[c1] * rsqrtf(var1 + EPSV);
  float shx = betaL[c0] - mu0 * scx;
  float shy = betaL[c1] - mu1 * scy;
  float ax = 0.f, ay = 0.f;
  for (int r = s + stripe; r < e; r += 8) {
    unsigned int u = h16[(size_t)r * 64 + slot];
    float2 t = __half22float2(*(__half2*)&u);
    ax += fmaxf(fmaf(t.x, scx, shx), 0.f);
    ay += fmaxf(fmaf(t.y, scy, shy), 0.f);
  }
  __shared__ float red[8][64][2];
  red[stripe][slot][0] = ax;
  red[stripe][slot][1] = ay;
  __syncthreads();
  if (threadIdx.x < 64) {
    int sl = threadIdx.x;
    float vx = 0.f, vy = 0.f;
#pragma unroll
    for (int st = 0; st < 8; ++st) {
      vx += red[st][sl][0];
      vy += red[st][sl][1];
    }
    float ic = invcnt[g];
    float* dst = pooled + (size_t)g * (3 * DIM) + level * DIM + 2 * sl;
    dst[0] = vx * ic;
    dst[1] = vy * ic;
  }
}

__global__ __launch_bounds__(512) void k_final(const float* __restrict__ pooled, const float* __restrict__ Wf,
                                               const float* __restrict__ bf, float* __restrict__ out) {
  int t = blockIdx.x * 512 + threadIdx.x;
  if (t >= NGRAPH * DIM) return;
  int j = t & (DIM - 1);
  int i = t >> 7;
  const float* prow = pooled + (size_t)i * (3 * DIM);
  float acc = bf[j];
  for (int k = 0; k < 3 * DIM; ++k) acc = fmaf(prow[k], Wf[(size_t)k * DIM + j], acc);
  out[t] = fmaxf(acc, 0.f);
}

// ---------------- launcher ----------------

extern "C" void kernel_launch(void* const* d_in, const int* in_sizes, int n_in,
                              void* d_out, int out_size, void* d_ws, size_t ws_size,
                              hipStream_t stream) {
  const float* x = (const float*)d_in[0];
  const int* ei = (const int*)d_in[1];
  const int* batch = (const int*)d_in[2];
  const float* W = (const float*)d_in[3];
  const float* b = (const float*)d_in[4];
  const float* gamma = (const float*)d_in[5];
  const float* beta = (const float*)d_in[6];
  const float* Wf = (const float*)d_in[7];
  const float* bf = (const float*)d_in[8];
  float* out = (float*)d_out;

  const int N = in_sizes[0] / DIM;   // 50000
  const int E = in_sizes[1] / 2;     // 800000

  char* base = (char*)d_ws;
  size_t off = 0;
  auto alloc = [&](size_t bytes) -> char* {
    char* p = base + off;
    off += (bytes + 255) & ~(size_t)255;
    return p;
  };
  unsigned int* h16 = (unsigned int*)alloc((size_t)N * DIM * 2);           // fp16 h, 64 u32/row
  unsigned int* T   = (unsigned int*)alloc((size_t)(N + 1) * DIM * 2);     // 4 panels [(N+1)][16] u32
  _Float16* W16T    = (_Float16*)alloc((size_t)6 * 16384 * 2);             // per-layer W^T fp16
  int* cnt          = (int*)alloc((size_t)N * 4);
  int* cursor       = (int*)alloc((size_t)N * 4);
  int* rowptr       = (int*)alloc((size_t)(N + 1) * 4);
  int* partial      = (int*)alloc(256 * 4);
  float* dinv       = (float*)alloc((size_t)N * 4);
  unsigned short* cols = (unsigned short*)alloc((size_t)(E + 32) * 2);     // +32 pad for overshoot
  float* statsAll   = (float*)alloc(6 * 256 * 4);  // per-layer colsum[128]|colsumsq[128]
  int* start        = (int*)alloc((NGRAPH + 1) * 4);
  float* invcnt     = (float*)alloc(NGRAPH * 4);
  float* pooled     = (float*)alloc((size_t)NGRAPH * 3 * DIM * 4);
  (void)ws_size;

  (void)hipMemsetAsync(cnt, 0, (size_t)N * 4, stream);
  (void)hipMemsetAsync(cursor, 0, (size_t)N * 4, stream);
  (void)hipMemsetAsync(statsAll, 0, 6 * 256 * 4, stream);

  int nbScan = (N + 511) / 512;  // 98
  k_count<<<(E + 255) / 256, 256, 0, stream>>>(ei, cnt, E);
  k_blocksum<<<nbScan, 512, 0, stream>>>(cnt, partial, N);
  k_scanpartials<<<1, 128, 0, stream>>>(partial, nbScan);
  k_scan_write<<<nbScan, 512, 0, stream>>>(cnt, partial, rowptr, dinv, N);
  k_fill<<<(E + 255) / 256, 256, 0, stream>>>(ei, rowptr, cursor, cols, E);
  k_gstart<<<(N + 255) / 256, 256, 0, stream>>>(batch, start, N);
  k_invcnt<<<1, 512, 0, stream>>>(start, invcnt);
  k_prepw<<<(6 * 16384 + 255) / 256, 256, 0, stream>>>(W, W16T);

  int gemmGrid = (N + 63) / 64;
  for (int l = 0; l < 6; ++l) {
    const float* statsPrev = (l == 0) ? nullptr : statsAll + (l - 1) * 256;
    const float* gP = (l == 0) ? gamma : gamma + (size_t)(l - 1) * DIM;
    const float* bP = (l == 0) ? beta : beta + (size_t)(l - 1) * DIM;
    k_gemm<<<gemmGrid, 256, 0, stream>>>((l == 0) ? x : nullptr, (l == 0) ? nullptr : h16,
                                         W16T + (size_t)l * 16384, statsPrev, gP, bP, dinv, T, N);
    k_agg<<<2048, 256, 0, stream>>>(T, rowptr, cols, dinv, b + (size_t)l * DIM, h16,
                                    statsAll + (size_t)l * 256, N);
    if (l & 1)
      k_pool<<<NGRAPH, 512, 0, stream>>>(h16, start, invcnt, statsAll + (size_t)l * 256,
                                         gamma + (size_t)l * DIM, beta + (size_t)l * DIM,
                                         pooled, l >> 1, N);
  }
  k_final<<<(NGRAPH * DIM + 511) / 512, 512, 0, stream>>>(pooled, Wf, bf, out);
}

// Round 13
// 670.072 us; speedup vs baseline: 2.6086x; 1.0351x over previous
//
#include <hip/hip_runtime.h>
#include <hip/hip_fp16.h>

// HierarchicalEncoder: 6× (GCN -> BN -> ReLU) with level pooling + final linear.
// Per layer:
//   tmp16 = dinv * BNReLU(h16) @ W16   (MFMA 16x16x32 f16 GEMM, W^T fp16 in LDS)
//   h16   = dinv[i]*(sum tmp16[col]) + b  (padded CSR incl. self; sentinel cols -> zero row;
//                                          u16 cols; 4-phase XCD-local 3.2MB panels)
// Per-layer BN stat buffers; BN applied inline by consumers (gemm staging, pool).

#define DIM 128
#define NGRAPH 512
#define EPSV 1e-5f

typedef _Float16 f16x8 __attribute__((ext_vector_type(8)));
typedef float f32x4 __attribute__((ext_vector_type(4)));

// ---------------- preprocessing ----------------

__global__ __launch_bounds__(256) void k_count(const int* __restrict__ ei, int* __restrict__ cnt, int E) {
  int e = blockIdx.x * 256 + threadIdx.x;
  if (e < E) atomicAdd(&cnt[ei[E + e]], 1);
}

// padded slot count per node: self + deg, ceil to 16
__device__ inline int padslots(int deg) { return (deg + 16) & ~15; }

__global__ __launch_bounds__(512) void k_blocksum(const int* __restrict__ cnt, int* __restrict__ partial, int N) {
  __shared__ int sd[512];
  int idx = blockIdx.x * 512 + threadIdx.x;
  int v = (idx < N) ? padslots(cnt[idx]) : 0;
  sd[threadIdx.x] = v;
  __syncthreads();
  for (int ofs = 256; ofs > 0; ofs >>= 1) {
    if (threadIdx.x < ofs) sd[threadIdx.x] += sd[threadIdx.x + ofs];
    __syncthreads();
  }
  if (threadIdx.x == 0) partial[blockIdx.x] = sd[0];
}

__global__ __launch_bounds__(128) void k_scanpartials(int* __restrict__ partial, int nb) {
  __shared__ int sp[128];
  int t = threadIdx.x;
  int v = (t < nb) ? partial[t] : 0;
  sp[t] = v;
  __syncthreads();
  for (int ofs = 1; ofs < 128; ofs <<= 1) {
    int a = (t >= ofs) ? sp[t - ofs] : 0;
    __syncthreads();
    sp[t] += a;
    __syncthreads();
  }
  if (t < nb) partial[t] = sp[t] - v;  // exclusive block offsets
}

__global__ __launch_bounds__(512) void k_scan_write(const int* __restrict__ cnt, const int* __restrict__ partial,
                                                    int* __restrict__ rowptr, float* __restrict__ dinv, int N) {
  __shared__ int sd[512];
  int tid = threadIdx.x;
  int idx = blockIdx.x * 512 + tid;
  int raw = (idx < N) ? cnt[idx] : 0;
  int v = (idx < N) ? padslots(raw) : 0;
  sd[tid] = v;
  __syncthreads();
  for (int ofs = 1; ofs < 512; ofs <<= 1) {
    int a = (tid >= ofs) ? sd[tid - ofs] : 0;
    __syncthreads();
    sd[tid] += a;
    __syncthreads();
  }
  if (idx < N) {
    int excl = partial[blockIdx.x] + sd[tid] - v;
    rowptr[idx] = excl;
    dinv[idx] = rsqrtf((float)(raw + 1));  // +1 for self loop
    if (idx == N - 1) rowptr[N] = excl + v;
  }
}

__global__ __launch_bounds__(256) void k_colsinit(unsigned int* __restrict__ cols32, int n32, unsigned int val) {
  int i = blockIdx.x * 256 + threadIdx.x;
  if (i < n32) cols32[i] = val;
}

// slot 0 of each node = self; cursor starts at 1
__global__ __launch_bounds__(256) void k_selfinit(const int* __restrict__ rowptr, int* __restrict__ cursor,
                                                  unsigned short* __restrict__ cols, int N) {
  int i = blockIdx.x * 256 + threadIdx.x;
  if (i >= N) return;
  cursor[i] = 1;
  cols[rowptr[i]] = (unsigned short)i;
}

__global__ __launch_bounds__(256) void k_fill(const int* __restrict__ ei, const int* __restrict__ rowptr,
                                              int* __restrict__ cursor, unsigned short* __restrict__ cols, int E) {
  int e = blockIdx.x * 256 + threadIdx.x;
  if (e >= E) return;
  int s = ei[e];
  int d = ei[E + e];
  int pos = rowptr[d] + atomicAdd(&cursor[d], 1);
  cols[pos] = (unsigned short)s;
}

__global__ __launch_bounds__(256) void k_gstart(const int* __restrict__ batch, int* __restrict__ start, int N) {
  int i = blockIdx.x * 256 + threadIdx.x;
  if (i >= N) return;
  int bi = batch[i];
  int prev = (i == 0) ? -1 : batch[i - 1];
  for (int g = prev + 1; g <= bi; ++g) start[g] = i;
  if (i == N - 1) {
    for (int g = bi + 1; g <= NGRAPH; ++g) start[g] = N;
  }
}

__global__ __launch_bounds__(512) void k_invcnt(const int* __restrict__ start, float* __restrict__ invcnt) {
  int g = threadIdx.x;
  if (g < NGRAPH) {
    int c = start[g + 1] - start[g];
    invcnt[g] = 1.0f / (float)max(c, 1);
  }
}

// W16T[l][n][k] = fp16(W[l][k][n]) — B-operand layout for MFMA (contiguous k per col)
__global__ __launch_bounds__(256) void k_prepw(const float* __restrict__ W, _Float16* __restrict__ W16T) {
  int idx = blockIdx.x * 256 + threadIdx.x;
  if (idx >= 6 * 16384) return;
  int l = idx >> 14, rem = idx & 16383;
  int k = rem >> 7, n = rem & 127;
  W16T[(size_t)l * 16384 + (size_t)n * 128 + k] = (_Float16)W[(size_t)l * 16384 + (size_t)k * 128 + n];
}

// ---------------- per-layer kernels ----------------

#define PITCH 136  // padded halves per LDS row (bank-conflict break)

// tmp16 = dinv[row] * act(A) @ W  via MFMA f16; fp16 panels [(N+1)][16] u32; row N = zeros.
// 64 rows/block, 4 waves; wave w = rows 16w..16w+15, all 128 cols.
// act = relu(sc*a+sh) with sc/sh computed inline from prev-layer raw stats, or identity (l=0).
__global__ __launch_bounds__(256) void k_gemm(const float* __restrict__ A32,         // layer-0 x | nullptr
                                              const unsigned int* __restrict__ A16,  // h16 | nullptr
                                              const _Float16* __restrict__ W16T,     // [128 n][128 k]
                                              const float* __restrict__ statsPrev,   // raw sums | nullptr
                                              const float* __restrict__ gammaP, const float* __restrict__ betaP,
                                              const float* __restrict__ dinv,
                                              unsigned int* __restrict__ T, int N) {
  __shared__ _Float16 sW[128 * PITCH];
  __shared__ _Float16 sA[64 * PITCH];
  __shared__ float sScSh[256];
  int tid = threadIdx.x;
  size_t pstride = (size_t)(N + 1) * 16;
  if (blockIdx.x == 0 && tid < 64) {  // zero-row of each panel (sentinel-gather target)
    int p = tid >> 4, sl = tid & 15;
    T[(size_t)p * pstride + (size_t)N * 16 + sl] = 0u;
  }
  if (statsPrev && tid < 128) {  // inline BN scale/shift from raw sums
    float invN = 1.f / (float)N;
    float mu = statsPrev[tid] * invN;
    float var = statsPrev[128 + tid] * invN - mu * mu;
    float sc = gammaP[tid] * rsqrtf(var + EPSV);
    sScSh[tid] = sc;
    sScSh[128 + tid] = betaP[tid] - mu * sc;
  }
  // stage W^T into LDS (padded rows)
#pragma unroll
  for (int i = 0; i < 16; ++i) {
    int f = (tid + i * 256) * 4;  // f16 index, 4 per thread-step
    int n = f >> 7, k = f & 127;
    *(uint2*)&sW[n * PITCH + k] = *(const uint2*)&W16T[n * 128 + k];
  }
  __syncthreads();  // sScSh ready for sA staging
  int row0 = blockIdx.x * 64;
#pragma unroll
  for (int i = 0; i < 8; ++i) {
    int f = (tid + i * 256) * 4;
    int r = f >> 7, c = f & 127;
    int row = row0 + r;
    uint2 outp = make_uint2(0u, 0u);
    if (row < N) {
      float v0, v1, v2, v3;
      if (statsPrev) {
        uint2 u = *(const uint2*)&A16[(size_t)row * 64 + (c >> 1)];
        float2 lo = __half22float2(*(__half2*)&u.x);
        float2 hi = __half22float2(*(__half2*)&u.y);
        v0 = fmaxf(fmaf(lo.x, sScSh[c], sScSh[128 + c]), 0.f);
        v1 = fmaxf(fmaf(lo.y, sScSh[c + 1], sScSh[128 + c + 1]), 0.f);
        v2 = fmaxf(fmaf(hi.x, sScSh[c + 2], sScSh[128 + c + 2]), 0.f);
        v3 = fmaxf(fmaf(hi.y, sScSh[c + 3], sScSh[128 + c + 3]), 0.f);
      } else {
        float4 v = *(const float4*)&A32[(size_t)row * 128 + c];
        v0 = v.x; v1 = v.y; v2 = v.z; v3 = v.w;
      }
      __half2 h0 = __floats2half2_rn(v0, v1);
      __half2 h1 = __floats2half2_rn(v2, v3);
      outp = make_uint2(*(unsigned int*)&h0, *(unsigned int*)&h1);
    }
    *(uint2*)&sA[r * PITCH + c] = outp;
  }
  __syncthreads();
  // MFMA: wave w -> rows 16w..16w+15; 8 col-tiles x 4 K-steps
  int w = tid >> 6;
  int l = tid & 63;
  int m = l & 15, kg = l >> 4;
  int rowbase = 16 * w;
  f16x8 af[4];
#pragma unroll
  for (int ks = 0; ks < 4; ++ks)
    af[ks] = *(const f16x8*)&sA[(rowbase + m) * PITCH + ks * 32 + kg * 8];
  f32x4 acc[8] = {};
#pragma unroll
  for (int t8 = 0; t8 < 8; ++t8) {
#pragma unroll
    for (int ks = 0; ks < 4; ++ks) {
      f16x8 bf = *(const f16x8*)&sW[(t8 * 16 + m) * PITCH + ks * 32 + kg * 8];
      acc[t8] = __builtin_amdgcn_mfma_f32_16x16x32_f16(af[ks], bf, acc[t8], 0, 0, 0);
    }
  }
  // epilogue: D col = 16*t8 + (lane&15), row = rowbase + (lane>>4)*4 + j
  float dv[4];
#pragma unroll
  for (int j = 0; j < 4; ++j) {
    int row = row0 + rowbase + kg * 4 + j;
    dv[j] = (row < N) ? dinv[row] : 0.f;
  }
#pragma unroll
  for (int t8 = 0; t8 < 8; ++t8) {
#pragma unroll
    for (int j = 0; j < 4; ++j)
      sA[(rowbase + kg * 4 + j) * PITCH + t8 * 16 + m] = (_Float16)(acc[t8][j] * dv[j]);
  }
  __syncthreads();
  // cooperative packed store into the 4 column panels
#pragma unroll
  for (int i = 0; i < 8; ++i) {
    int idx = tid + i * 256;
    int r = idx >> 5, q = idx & 31;  // q = uint2 group (4 cols)
    int row = row0 + r;
    if (row < N) {
      uint2 val = *(const uint2*)((const char*)sA + r * (PITCH * 2) + q * 8);
      int p = q >> 3, psl = (q & 7) * 2;
      *(uint2*)&T[(size_t)p * pstride + (size_t)row * 16 + psl] = val;
    }
  }
}

// Phase p (= blockIdx&3): gather 32 cols from the L2-resident panel.
// Padded CSR (self included, sentinel=N -> zero row). Wave = 4 quarters x 16 half2 slots;
// 16-slot batches: each quarter loads 4 packed u16 cols (one uint2) + 4 gathers.
__global__ __launch_bounds__(256) void k_agg(const unsigned int* __restrict__ T, const int* __restrict__ rowptr,
                                             const unsigned short* __restrict__ cols, const float* __restrict__ dinv,
                                             const float* __restrict__ bias, unsigned int* __restrict__ hout,
                                             float* __restrict__ stats, int N) {
  int phase = blockIdx.x & 3;
  int chunk = blockIdx.x >> 2;
  int nchunks = gridDim.x >> 2;
  int tid = threadIdx.x;
  int wid = __builtin_amdgcn_readfirstlane(tid >> 6);
  int lane = tid & 63;
  int sub = lane >> 4;   // quarter 0..3
  int slot = lane & 15;  // half2 slot (cols phase*32 + 2slot, +1)
  const unsigned int* __restrict__ Tp = T + (size_t)phase * (N + 1) * 16;
  float bx = bias[phase * 32 + 2 * slot];
  float by = bias[phase * 32 + 2 * slot + 1];
  int gwave = chunk * 4 + wid;
  int nwaves = nchunks * 4;
  float sum0 = 0.f, sum1 = 0.f, sq0 = 0.f, sq1 = 0.f;
  for (int i = gwave; i < N; i += nwaves) {
    float ax = 0.f, ay = 0.f;
    int beg = rowptr[i];
    int nb = (rowptr[i + 1] - beg) >> 4;
    const unsigned short* cp = cols + beg + sub * 4;
    for (int b = 0; b < nb; ++b, cp += 16) {
      uint2 cw = *(const uint2*)cp;  // 4 packed u16 col indices (uniform per quarter)
      int s0 = cw.x & 0xFFFF, s1 = cw.x >> 16;
      int s2 = cw.y & 0xFFFF, s3 = cw.y >> 16;
      unsigned int u0 = Tp[(size_t)s0 * 16 + slot];
      unsigned int u1 = Tp[(size_t)s1 * 16 + slot];
      unsigned int u2 = Tp[(size_t)s2 * 16 + slot];
      unsigned int u3 = Tp[(size_t)s3 * 16 + slot];
      float2 t0 = __half22float2(*(__half2*)&u0);
      float2 t1 = __half22float2(*(__half2*)&u1);
      float2 t2 = __half22float2(*(__half2*)&u2);
      float2 t3 = __half22float2(*(__half2*)&u3);
      ax += t0.x + t1.x;
      ay += t0.y + t1.y;
      ax += t2.x + t3.x;
      ay += t2.y + t3.y;
    }
    ax += __shfl_xor(ax, 16);
    ay += __shfl_xor(ay, 16);
    ax += __shfl_xor(ax, 32);
    ay += __shfl_xor(ay, 32);
    if (sub == 0) {
      float di = dinv[i];
      ax = fmaf(di, ax, bx);
      ay = fmaf(di, ay, by);
      __half2 hp = __floats2half2_rn(ax, ay);
      hout[(size_t)i * 64 + phase * 16 + slot] = *(unsigned int*)&hp;
      sum0 += ax;
      sum1 += ay;
      sq0 = fmaf(ax, ax, sq0);
      sq1 = fmaf(ay, ay, sq1);
    }
  }
  __shared__ float red[4][16][4];
  if (sub == 0) {
    red[wid][slot][0] = sum0;
    red[wid][slot][1] = sum1;
    red[wid][slot][2] = sq0;
    red[wid][slot][3] = sq1;
  }
  __syncthreads();
  if (tid < 16) {
    int sl = tid;
    float a0 = red[0][sl][0] + red[1][sl][0] + red[2][sl][0] + red[3][sl][0];
    float a1 = red[0][sl][1] + red[1][sl][1] + red[2][sl][1] + red[3][sl][1];
    float q0 = red[0][sl][2] + red[1][sl][2] + red[2][sl][2] + red[3][sl][2];
    float q1 = red[0][sl][3] + red[1][sl][3] + red[2][sl][3] + red[3][sl][3];
    int c0 = phase * 32 + 2 * sl;
    atomicAdd(&stats[c0], a0);
    atomicAdd(&stats[c0 + 1], a1);
    atomicAdd(&stats[DIM + c0], q0);
    atomicAdd(&stats[DIM + c0 + 1], q1);
  }
}

// pool mean of relu(sc*h+sh) per graph; sc/sh computed inline from raw stats
__global__ __launch_bounds__(512) void k_pool(const unsigned int* __restrict__ h16, const int* __restrict__ start,
                                              const float* __restrict__ invcnt, const float* __restrict__ statsL,
                                              const float* __restrict__ gammaL, const float* __restrict__ betaL,
                                              float* __restrict__ pooled, int level, int N) {
  int g = blockIdx.x;
  int s = start[g], e = start[g + 1];
  int slot = threadIdx.x & 63;   // u32 slot = cols 2slot, 2slot+1
  int stripe = threadIdx.x >> 6; // 0..7
  float invN = 1.f / (float)N;
  int c0 = 2 * slot, c1 = c0 + 1;
  float mu0 = statsL[c0] * invN, mu1 = statsL[c1] * invN;
  float var0 = statsL[DIM + c0] * invN - mu0 * mu0;
  float var1 = statsL[DIM + c1] * invN - mu1 * mu1;
  float scx = gammaL[c0] * rsqrtf(var0 + EPSV);
  float scy = gammaL[c1] * rsqrtf(var1 + EPSV);
  float shx = betaL[c0] - mu0 * scx;
  float shy = betaL[c1] - mu1 * scy;
  float ax = 0.f, ay = 0.f;
  for (int r = s + stripe; r < e; r += 8) {
    unsigned int u = h16[(size_t)r * 64 + slot];
    float2 t = __half22float2(*(__half2*)&u);
    ax += fmaxf(fmaf(t.x, scx, shx), 0.f);
    ay += fmaxf(fmaf(t.y, scy, shy), 0.f);
  }
  __shared__ float red[8][64][2];
  red[stripe][slot][0] = ax;
  red[stripe][slot][1] = ay;
  __syncthreads();
  if (threadIdx.x < 64) {
    int sl = threadIdx.x;
    float vx = 0.f, vy = 0.f;
#pragma unroll
    for (int st = 0; st < 8; ++st) {
      vx += red[st][sl][0];
      vy += red[st][sl][1];
    }
    float ic = invcnt[g];
    float* dst = pooled + (size_t)g * (3 * DIM) + level * DIM + 2 * sl;
    dst[0] = vx * ic;
    dst[1] = vy * ic;
  }
}

__global__ __launch_bounds__(512) void k_final(const float* __restrict__ pooled, const float* __restrict__ Wf,
                                               const float* __restrict__ bf, float* __restrict__ out) {
  int t = blockIdx.x * 512 + threadIdx.x;
  if (t >= NGRAPH * DIM) return;
  int j = t & (DIM - 1);
  int i = t >> 7;
  const float* prow = pooled + (size_t)i * (3 * DIM);
  float acc = bf[j];
  for (int k = 0; k < 3 * DIM; ++k) acc = fmaf(prow[k], Wf[(size_t)k * DIM + j], acc);
  out[t] = fmaxf(acc, 0.f);
}

// ---------------- launcher ----------------

extern "C" void kernel_launch(void* const* d_in, const int* in_sizes, int n_in,
                              void* d_out, int out_size, void* d_ws, size_t ws_size,
                              hipStream_t stream) {
  const float* x = (const float*)d_in[0];
  const int* ei = (const int*)d_in[1];
  const int* batch = (const int*)d_in[2];
  const float* W = (const float*)d_in[3];
  const float* b = (const float*)d_in[4];
  const float* gamma = (const float*)d_in[5];
  const float* beta = (const float*)d_in[6];
  const float* Wf = (const float*)d_in[7];
  const float* bf = (const float*)d_in[8];
  float* out = (float*)d_out;

  const int N = in_sizes[0] / DIM;   // 50000
  const int E = in_sizes[1] / 2;     // 800000

  char* base = (char*)d_ws;
  size_t off = 0;
  auto alloc = [&](size_t bytes) -> char* {
    char* p = base + off;
    off += (bytes + 255) & ~(size_t)255;
    return p;
  };
  const size_t colsCap = (size_t)E + 16 * (size_t)N + 64;  // padded-CSR worst case (u16 count)
  unsigned int* h16 = (unsigned int*)alloc((size_t)N * DIM * 2);           // fp16 h, 64 u32/row
  unsigned int* T   = (unsigned int*)alloc((size_t)(N + 1) * DIM * 2);     // 4 panels [(N+1)][16] u32
  _Float16* W16T    = (_Float16*)alloc((size_t)6 * 16384 * 2);             // per-layer W^T fp16
  int* cnt          = (int*)alloc((size_t)N * 4);
  int* cursor       = (int*)alloc((size_t)N * 4);
  int* rowptr       = (int*)alloc((size_t)(N + 1) * 4);
  int* partial      = (int*)alloc(256 * 4);
  float* dinv       = (float*)alloc((size_t)N * 4);
  unsigned short* cols = (unsigned short*)alloc(colsCap * 2);
  float* statsAll   = (float*)alloc(6 * 256 * 4);  // per-layer colsum[128]|colsumsq[128]
  int* start        = (int*)alloc((NGRAPH + 1) * 4);
  float* invcnt     = (float*)alloc(NGRAPH * 4);
  float* pooled     = (float*)alloc((size_t)NGRAPH * 3 * DIM * 4);
  (void)ws_size;

  (void)hipMemsetAsync(cnt, 0, (size_t)N * 4, stream);
  (void)hipMemsetAsync(statsAll, 0, 6 * 256 * 4, stream);

  int nbScan = (N + 511) / 512;  // 98
  k_count<<<(E + 255) / 256, 256, 0, stream>>>(ei, cnt, E);
  k_blocksum<<<nbScan, 512, 0, stream>>>(cnt, partial, N);
  k_scanpartials<<<1, 128, 0, stream>>>(partial, nbScan);
  k_scan_write<<<nbScan, 512, 0, stream>>>(cnt, partial, rowptr, dinv, N);
  int n32 = (int)(colsCap / 2);
  unsigned int sentinel = ((unsigned int)N << 16) | (unsigned int)N;
  k_colsinit<<<(n32 + 255) / 256, 256, 0, stream>>>((unsigned int*)cols, n32, sentinel);
  k_selfinit<<<(N + 255) / 256, 256, 0, stream>>>(rowptr, cursor, cols, N);
  k_fill<<<(E + 255) / 256, 256, 0, stream>>>(ei, rowptr, cursor, cols, E);
  k_gstart<<<(N + 255) / 256, 256, 0, stream>>>(batch, start, N);
  k_invcnt<<<1, 512, 0, stream>>>(start, invcnt);
  k_prepw<<<(6 * 16384 + 255) / 256, 256, 0, stream>>>(W, W16T);

  int gemmGrid = (N + 63) / 64;
  for (int l = 0; l < 6; ++l) {
    const float* statsPrev = (l == 0) ? nullptr : statsAll + (l - 1) * 256;
    const float* gP = (l == 0) ? gamma : gamma + (size_t)(l - 1) * DIM;
    const float* bP = (l == 0) ? beta : beta + (size_t)(l - 1) * DIM;
    k_gemm<<<gemmGrid, 256, 0, stream>>>((l == 0) ? x : nullptr, (l == 0) ? nullptr : h16,
                                         W16T + (size_t)l * 16384, statsPrev, gP, bP, dinv, T, N);
    k_agg<<<2048, 256, 0, stream>>>(T, rowptr, cols, dinv, b + (size_t)l * DIM, h16,
                                    statsAll + (size_t)l * 256, N);
    if (l & 1)
      k_pool<<<NGRAPH, 512, 0, stream>>>(h16, start, invcnt, statsAll + (size_t)l * 256,
                                         gamma + (size_t)l * DIM, beta + (size_t)l * DIM,
                                         pooled, l >> 1, N);
  }
  k_final<<<(NGRAPH * DIM + 511) / 512, 512, 0, stream>>>(pooled, Wf, bf, out);
}